// Round 2
// baseline (588.429 us; speedup 1.0000x reference)
//
#include <hip/hip_runtime.h>
#include <math.h>

// Problem constants (MambaBlock): B=2, L=4096, D=2048, H=32, DS=64, K=4
#define BB   2
#define LL   4096
#define DD   2048
#define HH   32
#define DSS  64
#define MM   (BB * LL)        // 8192 rows
#define N3   (3 * HH * DSS)   // 6144
#define NCH  64               // scan chunks
#define CLN  64               // steps per chunk (NCH*CLN == LL)
#define EPSF 1e-6f
#define TR_NBX 320            // transpose blocks in n (64 gp + 64 op + 192 pp)
#define TR_NBY (DD / 32)      // 64 transpose blocks in k
#define NT   (DD / 64)        // 32 K-tiles of 64
#define GT_NB (DD / 256)      // 8 gate n-tiles (256-wide)
#define PJ_NB (N3 / 256)      // 24 proj n-tiles

typedef unsigned short bf16;  // raw bf16 bits — we own the representation
typedef __attribute__((ext_vector_type(8))) short bf16x8;  // MFMA A/B frag (4 VGPRs)
typedef __attribute__((ext_vector_type(4))) float f32x4;   // MFMA C/D frag

__device__ __forceinline__ float bf2f(bf16 u) {
    union { unsigned int i; float f; } v;
    v.i = ((unsigned int)u) << 16;
    return v.f;
}
__device__ __forceinline__ bf16 f2bf(float f) {
    union { float f; unsigned int u; } v;
    v.f = f;
    unsigned int r = (v.u >> 16) & 1u;       // round to nearest even
    return (bf16)((v.u + 0x7fffu + r) >> 16);
}
__device__ __forceinline__ float sigmoidf_(float v) {
    return 1.0f / (1.0f + __expf(-v));
}
__device__ __forceinline__ void gload16(const void* g, void* l) {
    __builtin_amdgcn_global_load_lds(
        (const __attribute__((address_space(1))) void*)g,
        (__attribute__((address_space(3))) void*)l, 16, 0, 0);
}

#define SBAR()  asm volatile("s_barrier" ::: "memory")
#define LGKM0() asm volatile("s_waitcnt lgkmcnt(0)" ::: "memory")
#define VMC(n)  asm volatile("s_waitcnt vmcnt(" #n ")" ::: "memory")

// -------------------- RMSNorm + all 3 weight transposes in ONE dispatch -----
// blocks [0, MM): rms row; blocks [MM, MM + TR_NBX*TR_NBY): transpose tiles.
__global__ __launch_bounds__(256) void rms_transpose(const float* __restrict__ x,
                                                     const float* __restrict__ w,
                                                     bf16* __restrict__ xn,
                                                     const float* __restrict__ gp_w,
                                                     const float* __restrict__ op_w,
                                                     const float* __restrict__ pp_w,
                                                     bf16* __restrict__ gp_wT,
                                                     bf16* __restrict__ op_wT,
                                                     bf16* __restrict__ pp_wT) {
    __shared__ float sh[32 * 33];
    int t = threadIdx.x;
    if (blockIdx.x < MM) {
        // ---- RMSNorm row ----
        int row = blockIdx.x;
        const float4* x4 = (const float4*)(x + (size_t)row * DD);
        ushort4* o4 = (ushort4*)(xn + (size_t)row * DD);
        const float4* w4 = (const float4*)w;
        float4 v0 = x4[t], v1 = x4[t + 256];
        float ss = v0.x * v0.x + v0.y * v0.y + v0.z * v0.z + v0.w * v0.w +
                   v1.x * v1.x + v1.y * v1.y + v1.z * v1.z + v1.w * v1.w;
#pragma unroll
        for (int off = 32; off >= 1; off >>= 1) ss += __shfl_down(ss, off, 64);
        if ((t & 63) == 0) sh[t >> 6] = ss;
        __syncthreads();
        float tot = sh[0] + sh[1] + sh[2] + sh[3];
        float inv = 1.0f / sqrtf(tot * (1.0f / DD) + EPSF);
        float4 wa = w4[t], wb = w4[t + 256];
        ushort4 r0, r1;
        r0.x = f2bf(v0.x * inv * wa.x); r0.y = f2bf(v0.y * inv * wa.y);
        r0.z = f2bf(v0.z * inv * wa.z); r0.w = f2bf(v0.w * inv * wa.w);
        r1.x = f2bf(v1.x * inv * wb.x); r1.y = f2bf(v1.y * inv * wb.y);
        r1.z = f2bf(v1.z * inv * wb.z); r1.w = f2bf(v1.w * inv * wb.w);
        o4[t] = r0; o4[t + 256] = r1;
    } else {
        // ---- weight transpose tile (32k x 32n), fp32 -> bf16 ----
        int id = blockIdx.x - MM;
        int bx = id % TR_NBX;
        int k0 = (id / TR_NBX) << 5;
        const float* W; bf16* WT; int Ndim;
        if (bx < 64)       { W = gp_w; WT = gp_wT; Ndim = DD; }
        else if (bx < 128) { W = op_w; WT = op_wT; Ndim = DD; bx -= 64; }
        else               { W = pp_w; WT = pp_wT; Ndim = N3; bx -= 128; }
        int n0 = bx << 5;
        float (*tl)[33] = (float (*)[33])sh;
        int tx = t & 31, ty = t >> 5;           // load: 8 k-rows x 32 n
#pragma unroll
        for (int i = 0; i < 32; i += 8)
            tl[ty + i][tx] = W[(size_t)(k0 + ty + i) * Ndim + n0 + tx];
        __syncthreads();
        int tx2 = t & 15, ty2 = t >> 4;         // store: ushort2 along k
#pragma unroll
        for (int i = 0; i < 32; i += 16) {
            int n = ty2 + i;
            ushort2 v = { f2bf(tl[tx2 * 2][n]), f2bf(tl[tx2 * 2 + 1][n]) };
            *(ushort2*)&WT[(size_t)(n0 + n) * DD + k0 + tx2 * 2] = v;
        }
    }
}

// ----------------------------------------------------- causal conv + SiLU ---
// Sliding-window: thread owns 4 d's (ushort4), walks CONV_LC l's.
#define CONV_LC 16
__global__ __launch_bounds__(256) void conv_silu_kernel(const bf16* __restrict__ xn,
                                                        const float* __restrict__ cw,
                                                        const float* __restrict__ cb,
                                                        bf16* __restrict__ xc) {
    int b = blockIdx.z;
    int l0 = blockIdx.x * CONV_LC;
    int d0 = blockIdx.y * 1024 + threadIdx.x * 4;
    float4 w[4];
    float bias[4];
#pragma unroll
    for (int j = 0; j < 4; ++j) {
        w[j] = ((const float4*)cw)[d0 + j];
        bias[j] = cb[d0 + j];
    }
    float win[3][4];
#pragma unroll
    for (int k = 0; k < 3; ++k) {
        int l = l0 - 3 + k;
        if (l >= 0) {
            ushort4 v = *(const ushort4*)&xn[((size_t)b * LL + l) * DD + d0];
            win[k][0] = bf2f(v.x); win[k][1] = bf2f(v.y);
            win[k][2] = bf2f(v.z); win[k][3] = bf2f(v.w);
        } else {
            win[k][0] = win[k][1] = win[k][2] = win[k][3] = 0.0f;
        }
    }
    size_t off = ((size_t)b * LL + l0) * DD + d0;
#pragma unroll 4
    for (int i = 0; i < CONV_LC; ++i) {
        ushort4 v = *(const ushort4*)&xn[off];
        float cur[4] = {bf2f(v.x), bf2f(v.y), bf2f(v.z), bf2f(v.w)};
        ushort4 o;
#pragma unroll
        for (int j = 0; j < 4; ++j) {
            float acc = bias[j] + win[0][j] * w[j].x + win[1][j] * w[j].y +
                        win[2][j] * w[j].z + cur[j] * w[j].w;
            float s = acc * sigmoidf_(acc);
            ((unsigned short*)&o)[j] = f2bf(s);
        }
        *(ushort4*)&xc[off] = o;
#pragma unroll
        for (int j = 0; j < 4; ++j) {
            win[0][j] = win[1][j]; win[1][j] = win[2][j]; win[2][j] = cur[j];
        }
        off += DD;
    }
}

// --------------- 256x256 8-phase MFMA GEMM (T2+T3+T4+T5, deep prefetch) -----
// 8 waves (2M x 4N), per-wave 128x64 output split over both halves.
// LDS [2 buf][4 halves: A0,A1,B0,B1][128x64 chunk-swizzled] = 128 KiB.
// Per K-tile: 4 quadrant phases Q00,Q01,Q11,Q10 (frag reuse -> 24 ds_read).
// DEEP stage stream: during tile tau we stage tile tau+2 into the CURRENT
// buffer, each half staged right after the phase that did its last ds_read
// (WAR safe via the phase-closing barrier):
//   ph1: A0,B0(tau+2)   ph2: B1(tau+2)   ph3: A1(tau+2)
// => tile tau+1's 8 loads were all issued during tau-1; the single per-tile
// vmcnt(8) (after ph3's MFMA) gives them 4-6 phases (~1000 cyc) of slack
// and leaves tile tau+2's 8 loads in flight across the barrier (T4).
template <int EPI, typename OutT>
__device__ __forceinline__ void gemm_tile256(const bf16* __restrict__ A,
                                             const bf16* __restrict__ Bt,
                                             const float* __restrict__ bias,
                                             const float* __restrict__ add,
                                             OutT* __restrict__ out,
                                             int Ndim, int m0, int n0,
                                             bf16* lds) {
    const int tid  = threadIdx.x;
    const int wave = tid >> 6;
    const int lane = tid & 63;
    const int sr   = lane >> 3;                 // staging row-in-chunk 0..7
    const int gcol = ((lane & 7) ^ sr) << 3;    // pre-swizzled global col
    const bf16* gA = A  + (size_t)(m0 + wave * 16 + sr) * DD + gcol;
    const bf16* gB = Bt + (size_t)(n0 + wave * 16 + sr) * DD + gcol;
    const int ldst = wave * 1024 + lane * 8;    // linear LDS dest (elems)

    const int fr = lane & 15;
    const int kg = lane >> 4;
    const int f7 = fr & 7;
    const int wm = (wave >> 2) << 6;            // warp_m * 64
    const int wn = (wave & 3) << 5;             // warp_n * 32

    // stage one 128x64 half-tile: 2 x gload_lds(16B) per thread
    // halves: 0=A0, 1=A1, 2=B0, 3=B1
    auto STAGE = [&](int bufsel, int half, int tau) {
        const bf16* src = (half < 2 ? gA : gB) +
                          (size_t)((half & 1) << 7) * DD + tau * 64;
        bf16* dst = lds + bufsel * 32768 + half * 8192 + ldst;
        gload16(src, dst);
        gload16(src + 8 * DD, dst + 512);
    };

    f32x4 acc[8][4] = {};
    bf16x8 af[4][2], b0[2][2], b1[2][2];

    // prologue: fully stage tile0 (buf0) and tile1 (buf1); wait tile0 only.
    STAGE(0, 0, 0); STAGE(0, 2, 0); STAGE(0, 3, 0); STAGE(0, 1, 0);
    STAGE(1, 0, 1); STAGE(1, 2, 1); STAGE(1, 3, 1); STAGE(1, 1, 1);
    VMC(8);
    SBAR();

#pragma unroll 2
    for (int tau = 0; tau < NT; ++tau) {
        const int bsel = tau & 1;
        bf16* Ls = lds + bsel * 32768;
        // ---------- phase 0: read af0 (A0) + b0 (B0); Q00 -------------------
#pragma unroll
        for (int i = 0; i < 4; ++i)
#pragma unroll
            for (int ks = 0; ks < 2; ++ks)
                af[i][ks] = *(const bf16x8*)&Ls[(wm + i * 16 + fr) * 64 +
                                               ((((ks << 2) | kg) ^ f7) << 3)];
#pragma unroll
        for (int j = 0; j < 2; ++j)
#pragma unroll
            for (int ks = 0; ks < 2; ++ks)
                b0[j][ks] = *(const bf16x8*)&Ls[2 * 8192 + (wn + j * 16 + fr) * 64 +
                                               ((((ks << 2) | kg) ^ f7) << 3)];
        SBAR(); LGKM0();
        __builtin_amdgcn_sched_barrier(0);
        __builtin_amdgcn_s_setprio(1);
#pragma unroll
        for (int ks = 0; ks < 2; ++ks)
#pragma unroll
            for (int i = 0; i < 4; ++i)
#pragma unroll
                for (int j = 0; j < 2; ++j)
                    acc[i][j] = __builtin_amdgcn_mfma_f32_16x16x32_bf16(
                        af[i][ks], b0[j][ks], acc[i][j], 0, 0, 0);
        __builtin_amdgcn_sched_barrier(0);
        __builtin_amdgcn_s_setprio(0);
        SBAR();
        // ---------- phase 1: read b1 (B1); stage A0,B0(tau+2); Q01 ----------
#pragma unroll
        for (int j = 0; j < 2; ++j)
#pragma unroll
            for (int ks = 0; ks < 2; ++ks)
                b1[j][ks] = *(const bf16x8*)&Ls[3 * 8192 + (wn + j * 16 + fr) * 64 +
                                               ((((ks << 2) | kg) ^ f7) << 3)];
        if (tau + 2 < NT) { STAGE(bsel, 0, tau + 2); STAGE(bsel, 2, tau + 2); }
        SBAR(); LGKM0();
        __builtin_amdgcn_sched_barrier(0);
        __builtin_amdgcn_s_setprio(1);
#pragma unroll
        for (int ks = 0; ks < 2; ++ks)
#pragma unroll
            for (int i = 0; i < 4; ++i)
#pragma unroll
                for (int j = 0; j < 2; ++j)
                    acc[i][2 + j] = __builtin_amdgcn_mfma_f32_16x16x32_bf16(
                        af[i][ks], b1[j][ks], acc[i][2 + j], 0, 0, 0);
        __builtin_amdgcn_sched_barrier(0);
        __builtin_amdgcn_s_setprio(0);
        SBAR();
        // ---------- phase 2: read af1 (A1); stage B1(tau+2); Q11 ------------
#pragma unroll
        for (int i = 0; i < 4; ++i)
#pragma unroll
            for (int ks = 0; ks < 2; ++ks)
                af[i][ks] = *(const bf16x8*)&Ls[8192 + (wm + i * 16 + fr) * 64 +
                                               ((((ks << 2) | kg) ^ f7) << 3)];
        if (tau + 2 < NT) STAGE(bsel, 3, tau + 2);
        SBAR(); LGKM0();
        __builtin_amdgcn_sched_barrier(0);
        __builtin_amdgcn_s_setprio(1);
#pragma unroll
        for (int ks = 0; ks < 2; ++ks)
#pragma unroll
            for (int i = 0; i < 4; ++i)
#pragma unroll
                for (int j = 0; j < 2; ++j)
                    acc[4 + i][2 + j] = __builtin_amdgcn_mfma_f32_16x16x32_bf16(
                        af[i][ks], b1[j][ks], acc[4 + i][2 + j], 0, 0, 0);
        __builtin_amdgcn_sched_barrier(0);
        __builtin_amdgcn_s_setprio(0);
        SBAR();
        // ---------- phase 3: stage A1(tau+2); Q10; counted vmcnt AFTER mfma -
        if (tau + 2 < NT) STAGE(bsel, 1, tau + 2);
        SBAR();
        __builtin_amdgcn_sched_barrier(0);
        __builtin_amdgcn_s_setprio(1);
#pragma unroll
        for (int ks = 0; ks < 2; ++ks)
#pragma unroll
            for (int i = 0; i < 4; ++i)
#pragma unroll
                for (int j = 0; j < 2; ++j)
                    acc[4 + i][j] = __builtin_amdgcn_mfma_f32_16x16x32_bf16(
                        af[i][ks], b0[j][ks], acc[4 + i][j], 0, 0, 0);
        __builtin_amdgcn_sched_barrier(0);
        __builtin_amdgcn_s_setprio(0);
        if (tau < NT - 2) { VMC(8); } else { VMC(0); }
        SBAR();
    }

    // epilogue: C/D layout col(n)=lane&15, row(m)=kg*4+reg  [m89/m91 verified]
    const int baseRow = m0 + wm + (kg << 2);
    const int baseCol = n0 + wn + fr;
    float bia[4];
#pragma unroll
    for (int nf = 0; nf < 4; ++nf)
        bia[nf] = bias[baseCol + (nf >> 1) * 128 + (nf & 1) * 16];
#pragma unroll
    for (int mf = 0; mf < 8; ++mf) {
#pragma unroll
        for (int r = 0; r < 4; ++r) {
            int m = baseRow + (mf >> 2) * 128 + (mf & 3) * 16 + r;
            size_t rowoff = (size_t)m * Ndim + baseCol;
#pragma unroll
            for (int nf = 0; nf < 4; ++nf) {
                size_t off = rowoff + (nf >> 1) * 128 + (nf & 1) * 16;
                float v = acc[mf][nf][r] + bia[nf];
                if (EPI == 1) v = sigmoidf_(v);
                if (EPI == 2) v += add[off];
                if constexpr (sizeof(OutT) == 4)
                    ((float*)out)[off] = v;
                else
                    ((bf16*)out)[off] = f2bf(v);
            }
        }
    }
}

// gate GEMM + proj GEMM merged into one dispatch. 1024 blocks, XCD-swizzled.
__global__ __launch_bounds__(512, 2) void gemm_gateproj(const bf16* __restrict__ xc,
                                                        const bf16* __restrict__ gp_wT,
                                                        const float* __restrict__ gp_b,
                                                        bf16* __restrict__ gate,
                                                        const bf16* __restrict__ xn,
                                                        const bf16* __restrict__ pp_wT,
                                                        const float* __restrict__ pp_b,
                                                        bf16* __restrict__ p) {
    __shared__ __align__(16) bf16 lds[2 * 4 * 8192];   // 128 KiB
    int fid = blockIdx.x;                               // 1024 = 8 XCD * 128
    int f = (fid & 7) * 128 + (fid >> 3);               // bijective (1024%8==0)
    int by = f >> 5;                                    // m-tile 0..31
    int bx = f & 31;                                    // n-slot 0..31
    int m0 = by << 8;
    if (bx < GT_NB)
        gemm_tile256<1, bf16>(xc, gp_wT, gp_b, nullptr, gate, DD,
                              m0, bx << 8, lds);
    else
        gemm_tile256<0, bf16>(xn, pp_wT, pp_b, nullptr, p, N3,
                              m0, (bx - GT_NB) << 8, lds);
}

// final out GEMM: y = mixed @ op_w + op_b + x.  256 blocks = exactly 1/CU.
__global__ __launch_bounds__(512, 2) void gemm_out(const bf16* __restrict__ mixed,
                                                   const bf16* __restrict__ op_wT,
                                                   const float* __restrict__ op_b,
                                                   const float* __restrict__ x,
                                                   float* __restrict__ y) {
    __shared__ __align__(16) bf16 lds[2 * 4 * 8192];   // 128 KiB
    int fid = blockIdx.x;
    int f = (fid & 7) * 32 + (fid >> 3);                // bijective (256%8==0)
    int m0 = (f >> 3) << 8;
    int n0 = (f & 7) << 8;
    gemm_tile256<2, float>(mixed, op_wT, op_b, x, y, DD, m0, n0, lds);
}

// ------------------------------------------------------------- SSM scan -----
// p[b,l,h,j,s] (bf16); j=0 delta(pre-sigmoid), j=1 B, j=2 C.
// h = sigmoid(delta)*h + B;  ssm = C*h.

// phase 1: per-chunk affine composition (4 h's per 256-thread block)
__global__ __launch_bounds__(256) void scan_phase1(const bf16* __restrict__ p,
                                                   float* __restrict__ cA,
                                                   float* __restrict__ cB) {
    int c = blockIdx.x, b = blockIdx.z, s = threadIdx.x & 63;
    int h = blockIdx.y * 4 + (threadIdx.x >> 6);
    size_t base = ((size_t)(b * LL + c * CLN)) * N3 + h * (3 * DSS) + s;
    float a = 1.0f, bb = 0.0f;
#pragma unroll 8
    for (int i = 0; i < CLN; ++i) {
        float d = sigmoidf_(bf2f(p[base]));
        float Bv = bf2f(p[base + DSS]);
        a *= d;
        bb = d * bb + Bv;
        base += N3;
    }
    int idx = ((b * HH + h) * NCH + c) * DSS + s;
    cA[idx] = a;
    cB[idx] = bb;
}

// phase 3: per-block chunk-prefix from cA/cB, then replay fused with
// mixed = gate*C*h + (1-gate)*xn; block c==NCH-1 also emits h_last.
__global__ __launch_bounds__(256) void scan_phase3(const bf16* __restrict__ p,
                                                   const float* __restrict__ cA,
                                                   const float* __restrict__ cB,
                                                   const float* __restrict__ state,
                                                   const bf16* __restrict__ gate,
                                                   const bf16* __restrict__ xn,
                                                   bf16* __restrict__ mixed,
                                                   float* __restrict__ hlast) {
    int c = blockIdx.x, b = blockIdx.z, s = threadIdx.x & 63;
    int h = blockIdx.y * 4 + (threadIdx.x >> 6);
    // chunk prefix: compose chunks 0..c-1 onto the initial state
    float hp = state[(b * HH + h) * DSS + s];
    int cbase = ((b * HH + h) * NCH) * DSS + s;
    for (int cc = 0; cc < c; ++cc)
        hp = cA[cbase + cc * DSS] * hp + cB[cbase + cc * DSS];
    // replay + mix
    size_t prow = ((size_t)(b * LL + c * CLN)) * N3 + h * (3 * DSS) + s;
    size_t grow = ((size_t)(b * LL + c * CLN)) * DD + h * DSS + s;
#pragma unroll 4
    for (int i = 0; i < CLN; ++i) {
        float d = sigmoidf_(bf2f(p[prow]));
        float Bv = bf2f(p[prow + DSS]);
        float Cv = bf2f(p[prow + 2 * DSS]);
        hp = d * hp + Bv;
        float ssm = Cv * hp;
        float g = bf2f(gate[grow]);
        float xv = bf2f(xn[grow]);
        mixed[grow] = f2bf(g * ssm + (1.0f - g) * xv);
        prow += N3;
        grow += DD;
    }
    if (c == NCH - 1) hlast[(b * HH + h) * DSS + s] = hp;
}

// ---------------------------------------------------------------------------
extern "C" void kernel_launch(void* const* d_in, const int* in_sizes, int n_in,
                              void* d_out, int out_size, void* d_ws, size_t ws_size,
                              hipStream_t stream) {
    const float* x      = (const float*)d_in[0];
    const float* state  = (const float*)d_in[1];
    const float* norm_w = (const float*)d_in[2];
    const float* conv_w = (const float*)d_in[3];
    const float* conv_b = (const float*)d_in[4];
    const float* pp_w   = (const float*)d_in[5];
    const float* pp_b   = (const float*)d_in[6];
    const float* gp_w   = (const float*)d_in[7];
    const float* gp_b   = (const float*)d_in[8];
    const float* op_w   = (const float*)d_in[9];
    const float* op_b   = (const float*)d_in[10];

    float* y     = (float*)d_out;                 // M*D floats (64 MB)
    float* hlast = y + (size_t)MM * DD;           // B*H*DS floats

    // ws: xn 32MB | xcbuf 32MB (xc -> mixed) | p 96MB | cA,cB 2MB |
    //     gp_wT 8MB | op_wT 8MB                               total ~178MB
    // d_out y region (64MB): gate bf16 [0,32MB) | pp_wT bf16 [32,56MB)
    //   — both dead before gemm_out overwrites y with fp32 output.
    const size_t BHND = (size_t)BB * HH * NCH * DSS;
    char* ws = (char*)d_ws;
    bf16* xn    = (bf16*)ws;
    bf16* xcbuf = xn + (size_t)MM * DD;
    bf16* p     = xcbuf + (size_t)MM * DD;
    float* cA   = (float*)(p + (size_t)MM * N3);
    float* cB   = cA + BHND;
    bf16* gp_wT = (bf16*)(cB + BHND);
    bf16* op_wT = gp_wT + (size_t)DD * DD;
    bf16* gate  = (bf16*)y;                       // 32MB
    bf16* pp_wT = gate + (size_t)MM * DD;         // 24MB, in upper half of y
    bf16* mixed = xcbuf;

    // 1. RMSNorm + all three weight transposes (one dispatch)
    rms_transpose<<<MM + TR_NBX * TR_NBY, 256, 0, stream>>>(
        x, norm_w, xn, gp_w, op_w, pp_w, gp_wT, op_wT, pp_wT);
    // 2. causal conv + SiLU (sliding window)
    conv_silu_kernel<<<dim3(LL / CONV_LC, DD / 1024, BB), 256, 0, stream>>>(
        xn, conv_w, conv_b, xcbuf);
    // 3. gate = sigmoid(xc @ gp_w + gp_b)  AND  p = xn @ pp_w + pp_b (merged)
    gemm_gateproj<<<(GT_NB + PJ_NB) * (MM / 256), 512, 0, stream>>>(
        xcbuf, gp_wT, gp_b, gate, xn, pp_wT, pp_b, p);
    // 4. per-chunk scan summaries
    scan_phase1<<<dim3(NCH, HH / 4, BB), 256, 0, stream>>>(p, cA, cB);
    // 5. prefix + replay + mix + h_last (phase2 folded in)
    scan_phase3<<<dim3(NCH, HH / 4, BB), 256, 0, stream>>>(
        p, cA, cB, state, gate, xn, mixed, hlast);
    // 6. y = mixed @ op_w + op_b + x
    gemm_out<<<MM / 256 * (DD / 256), 512, 0, stream>>>(mixed, op_wT, op_b, x, y);
}

// Round 4
// 579.840 us; speedup vs baseline: 1.0148x; 1.0148x over previous
//
#include <hip/hip_runtime.h>
#include <math.h>

// Problem constants (MambaBlock): B=2, L=4096, D=2048, H=32, DS=64, K=4
#define BB   2
#define LL   4096
#define DD   2048
#define HH   32
#define DSS  64
#define MM   (BB * LL)        // 8192 rows
#define N3   (3 * HH * DSS)   // 6144
#define NCH  64               // scan chunks
#define CLN  64               // steps per chunk (NCH*CLN == LL)
#define EPSF 1e-6f
#define TR_NBX 320            // transpose blocks in n (64 gp + 64 op + 192 pp)
#define TR_NBY (DD / 32)      // 64 transpose blocks in k
#define NT   (DD / 64)        // 32 K-tiles of 64
#define GT_NB (DD / 256)      // 8 gate n-tiles (256-wide)
#define PJ_NB (N3 / 256)      // 24 proj n-tiles

typedef unsigned short bf16;  // raw bf16 bits — we own the representation
typedef __attribute__((ext_vector_type(8))) short bf16x8;  // MFMA A/B frag (4 VGPRs)
typedef __attribute__((ext_vector_type(4))) float f32x4;   // MFMA C/D frag

__device__ __forceinline__ float bf2f(bf16 u) {
    union { unsigned int i; float f; } v;
    v.i = ((unsigned int)u) << 16;
    return v.f;
}
__device__ __forceinline__ bf16 f2bf(float f) {
    union { float f; unsigned int u; } v;
    v.f = f;
    unsigned int r = (v.u >> 16) & 1u;       // round to nearest even
    return (bf16)((v.u + 0x7fffu + r) >> 16);
}
__device__ __forceinline__ float sigmoidf_(float v) {
    return 1.0f / (1.0f + __expf(-v));
}
__device__ __forceinline__ void gload16(const void* g, void* l) {
    __builtin_amdgcn_global_load_lds(
        (const __attribute__((address_space(1))) void*)g,
        (__attribute__((address_space(3))) void*)l, 16, 0, 0);
}

#define SBAR()  asm volatile("s_barrier" ::: "memory")
#define VMC(n)  asm volatile("s_waitcnt vmcnt(" #n ")" ::: "memory")

// -------------------- RMSNorm + all 3 weight transposes in ONE dispatch -----
// blocks [0, MM): rms row; blocks [MM, MM + TR_NBX*TR_NBY): transpose tiles.
__global__ __launch_bounds__(256) void rms_transpose(const float* __restrict__ x,
                                                     const float* __restrict__ w,
                                                     bf16* __restrict__ xn,
                                                     const float* __restrict__ gp_w,
                                                     const float* __restrict__ op_w,
                                                     const float* __restrict__ pp_w,
                                                     bf16* __restrict__ gp_wT,
                                                     bf16* __restrict__ op_wT,
                                                     bf16* __restrict__ pp_wT) {
    __shared__ float sh[32 * 33];
    int t = threadIdx.x;
    if (blockIdx.x < MM) {
        // ---- RMSNorm row ----
        int row = blockIdx.x;
        const float4* x4 = (const float4*)(x + (size_t)row * DD);
        ushort4* o4 = (ushort4*)(xn + (size_t)row * DD);
        const float4* w4 = (const float4*)w;
        float4 v0 = x4[t], v1 = x4[t + 256];
        float ss = v0.x * v0.x + v0.y * v0.y + v0.z * v0.z + v0.w * v0.w +
                   v1.x * v1.x + v1.y * v1.y + v1.z * v1.z + v1.w * v1.w;
#pragma unroll
        for (int off = 32; off >= 1; off >>= 1) ss += __shfl_down(ss, off, 64);
        if ((t & 63) == 0) sh[t >> 6] = ss;
        __syncthreads();
        float tot = sh[0] + sh[1] + sh[2] + sh[3];
        float inv = 1.0f / sqrtf(tot * (1.0f / DD) + EPSF);
        float4 wa = w4[t], wb = w4[t + 256];
        ushort4 r0, r1;
        r0.x = f2bf(v0.x * inv * wa.x); r0.y = f2bf(v0.y * inv * wa.y);
        r0.z = f2bf(v0.z * inv * wa.z); r0.w = f2bf(v0.w * inv * wa.w);
        r1.x = f2bf(v1.x * inv * wb.x); r1.y = f2bf(v1.y * inv * wb.y);
        r1.z = f2bf(v1.z * inv * wb.z); r1.w = f2bf(v1.w * inv * wb.w);
        o4[t] = r0; o4[t + 256] = r1;
    } else {
        // ---- weight transpose tile (32k x 32n), fp32 -> bf16 ----
        int id = blockIdx.x - MM;
        int bx = id % TR_NBX;
        int k0 = (id / TR_NBX) << 5;
        const float* W; bf16* WT; int Ndim;
        if (bx < 64)       { W = gp_w; WT = gp_wT; Ndim = DD; }
        else if (bx < 128) { W = op_w; WT = op_wT; Ndim = DD; bx -= 64; }
        else               { W = pp_w; WT = pp_wT; Ndim = N3; bx -= 128; }
        int n0 = bx << 5;
        float (*tl)[33] = (float (*)[33])sh;
        int tx = t & 31, ty = t >> 5;           // load: 8 k-rows x 32 n
#pragma unroll
        for (int i = 0; i < 32; i += 8)
            tl[ty + i][tx] = W[(size_t)(k0 + ty + i) * Ndim + n0 + tx];
        __syncthreads();
        int tx2 = t & 15, ty2 = t >> 4;         // store: ushort2 along k
#pragma unroll
        for (int i = 0; i < 32; i += 16) {
            int n = ty2 + i;
            ushort2 v = { f2bf(tl[tx2 * 2][n]), f2bf(tl[tx2 * 2 + 1][n]) };
            *(ushort2*)&WT[(size_t)(n0 + n) * DD + k0 + tx2 * 2] = v;
        }
    }
}

// ----------------------------------------------------- causal conv + SiLU ---
// Sliding-window: thread owns 4 d's (ushort4), walks CONV_LC l's.
#define CONV_LC 16
__global__ __launch_bounds__(256) void conv_silu_kernel(const bf16* __restrict__ xn,
                                                        const float* __restrict__ cw,
                                                        const float* __restrict__ cb,
                                                        bf16* __restrict__ xc) {
    int b = blockIdx.z;
    int l0 = blockIdx.x * CONV_LC;
    int d0 = blockIdx.y * 1024 + threadIdx.x * 4;
    float4 w[4];
    float bias[4];
#pragma unroll
    for (int j = 0; j < 4; ++j) {
        w[j] = ((const float4*)cw)[d0 + j];
        bias[j] = cb[d0 + j];
    }
    float win[3][4];
#pragma unroll
    for (int k = 0; k < 3; ++k) {
        int l = l0 - 3 + k;
        if (l >= 0) {
            ushort4 v = *(const ushort4*)&xn[((size_t)b * LL + l) * DD + d0];
            win[k][0] = bf2f(v.x); win[k][1] = bf2f(v.y);
            win[k][2] = bf2f(v.z); win[k][3] = bf2f(v.w);
        } else {
            win[k][0] = win[k][1] = win[k][2] = win[k][3] = 0.0f;
        }
    }
    size_t off = ((size_t)b * LL + l0) * DD + d0;
#pragma unroll 4
    for (int i = 0; i < CONV_LC; ++i) {
        ushort4 v = *(const ushort4*)&xn[off];
        float cur[4] = {bf2f(v.x), bf2f(v.y), bf2f(v.z), bf2f(v.w)};
        ushort4 o;
#pragma unroll
        for (int j = 0; j < 4; ++j) {
            float acc = bias[j] + win[0][j] * w[j].x + win[1][j] * w[j].y +
                        win[2][j] * w[j].z + cur[j] * w[j].w;
            float s = acc * sigmoidf_(acc);
            ((unsigned short*)&o)[j] = f2bf(s);
        }
        *(ushort4*)&xc[off] = o;
#pragma unroll
        for (int j = 0; j < 4; ++j) {
            win[0][j] = win[1][j]; win[1][j] = win[2][j]; win[2][j] = cur[j];
        }
        off += DD;
    }
}

// --------------- 256x256 8-phase MFMA GEMM (T2+T3+T4+T5) --------------------
// 8 waves (2M x 4N), per-wave 128x64 output split over both halves.
// LDS [2 buf][4 halves: A0,A1,B0,B1][128x64 chunk-swizzled] = 128 KiB.
// Per K-tile: 4 quadrant phases Q00,Q01,Q11,Q10 (frag reuse -> 24 ds_read).
// Stage stream (R1-proven): ph0 A1(tau+1), ph1 B0(tau+1), ph2 A0(tau+2),
// ph3 B1(tau+2) + VMC(4) (counted, never 0 in steady state).
// READ REBALANCE (this round): ph0 front-loads af0+b0+b1 (16 reads; all of
// tile tau's halves landed >=2 phases ago per VMC(4) analysis). af1's 8 reads
// issue at ph1's TAIL, after Q01 frees af's registers (VGPR-neutral).
// No forced lgkmcnt(0): the compiler emits counted per-use waits, so Q00
// waits only its 12, b1 flies under Q00's MFMA, af1 under ph1->ph2 barriers.
// Q10 (ph3) and Q11 (ph2) have zero fresh-read waits.
template <int EPI, typename OutT>
__device__ __forceinline__ void gemm_tile256(const bf16* __restrict__ A,
                                             const bf16* __restrict__ Bt,
                                             const float* __restrict__ bias,
                                             const float* __restrict__ add,
                                             OutT* __restrict__ out,
                                             int Ndim, int m0, int n0,
                                             bf16* lds) {
    const int tid  = threadIdx.x;
    const int wave = tid >> 6;
    const int lane = tid & 63;
    const int sr   = lane >> 3;                 // staging row-in-chunk 0..7
    const int gcol = ((lane & 7) ^ sr) << 3;    // pre-swizzled global col
    const bf16* gA = A  + (size_t)(m0 + wave * 16 + sr) * DD + gcol;
    const bf16* gB = Bt + (size_t)(n0 + wave * 16 + sr) * DD + gcol;
    const int ldst = wave * 1024 + lane * 8;    // linear LDS dest (elems)

    const int fr = lane & 15;
    const int kg = lane >> 4;
    const int f7 = fr & 7;
    const int wm = (wave >> 2) << 6;            // warp_m * 64
    const int wn = (wave & 3) << 5;             // warp_n * 32

    // stage one 128x64 half-tile: 2 x gload_lds(16B) per thread
    // halves: 0=A0, 1=A1, 2=B0, 3=B1
    auto STAGE = [&](int bufsel, int half, int tau) {
        const bf16* src = (half < 2 ? gA : gB) +
                          (size_t)((half & 1) << 7) * DD + tau * 64;
        bf16* dst = lds + bufsel * 32768 + half * 8192 + ldst;
        gload16(src, dst);
        gload16(src + 8 * DD, dst + 512);
    };

    f32x4 acc[8][4] = {};
    bf16x8 af[4][2], b0[2][2], b1[2][2];

    // prologue: stage tile0 fully + tile1 {A0,B1}; wait tile0 (4 newest fly).
    STAGE(0, 0, 0); STAGE(0, 3, 0); STAGE(0, 1, 0); STAGE(0, 2, 0);
    STAGE(1, 0, 1); STAGE(1, 3, 1);
    VMC(4);
    SBAR();

#pragma unroll 2
    for (int tau = 0; tau < NT; ++tau) {
        const int bsel = tau & 1;
        bf16* Ls = lds + bsel * 32768;
        // --- phase 0: read af0+b0+b1 (16); stage A1(tau+1); Q00 = af0 x b0 --
#pragma unroll
        for (int i = 0; i < 4; ++i)
#pragma unroll
            for (int ks = 0; ks < 2; ++ks)
                af[i][ks] = *(const bf16x8*)&Ls[(wm + i * 16 + fr) * 64 +
                                               ((((ks << 2) | kg) ^ f7) << 3)];
#pragma unroll
        for (int j = 0; j < 2; ++j)
#pragma unroll
            for (int ks = 0; ks < 2; ++ks)
                b0[j][ks] = *(const bf16x8*)&Ls[2 * 8192 + (wn + j * 16 + fr) * 64 +
                                               ((((ks << 2) | kg) ^ f7) << 3)];
#pragma unroll
        for (int j = 0; j < 2; ++j)
#pragma unroll
            for (int ks = 0; ks < 2; ++ks)
                b1[j][ks] = *(const bf16x8*)&Ls[3 * 8192 + (wn + j * 16 + fr) * 64 +
                                               ((((ks << 2) | kg) ^ f7) << 3)];
        if (tau + 1 < NT) STAGE(bsel ^ 1, 1, tau + 1);
        SBAR();
        __builtin_amdgcn_sched_barrier(0);
        __builtin_amdgcn_s_setprio(1);
#pragma unroll
        for (int ks = 0; ks < 2; ++ks)
#pragma unroll
            for (int i = 0; i < 4; ++i)
#pragma unroll
                for (int j = 0; j < 2; ++j)
                    acc[i][j] = __builtin_amdgcn_mfma_f32_16x16x32_bf16(
                        af[i][ks], b0[j][ks], acc[i][j], 0, 0, 0);
        __builtin_amdgcn_s_setprio(0);
        __builtin_amdgcn_sched_barrier(0);
        SBAR();
        // --- phase 1: stage B0(tau+1); Q01 = af0 x b1; TAIL: read af1 (8) ---
        if (tau + 1 < NT) STAGE(bsel ^ 1, 2, tau + 1);
        SBAR();
        __builtin_amdgcn_sched_barrier(0);
        __builtin_amdgcn_s_setprio(1);
#pragma unroll
        for (int ks = 0; ks < 2; ++ks)
#pragma unroll
            for (int i = 0; i < 4; ++i)
#pragma unroll
                for (int j = 0; j < 2; ++j)
                    acc[i][2 + j] = __builtin_amdgcn_mfma_f32_16x16x32_bf16(
                        af[i][ks], b1[j][ks], acc[i][2 + j], 0, 0, 0);
        __builtin_amdgcn_s_setprio(0);
        __builtin_amdgcn_sched_barrier(0);
#pragma unroll
        for (int i = 0; i < 4; ++i)
#pragma unroll
            for (int ks = 0; ks < 2; ++ks)
                af[i][ks] = *(const bf16x8*)&Ls[8192 + (wm + i * 16 + fr) * 64 +
                                               ((((ks << 2) | kg) ^ f7) << 3)];
        SBAR();
        // --- phase 2: stage A0(tau+2); Q11 = af1 x b1 -----------------------
        if (tau + 2 < NT) STAGE(bsel, 0, tau + 2);
        SBAR();
        __builtin_amdgcn_sched_barrier(0);
        __builtin_amdgcn_s_setprio(1);
#pragma unroll
        for (int ks = 0; ks < 2; ++ks)
#pragma unroll
            for (int i = 0; i < 4; ++i)
#pragma unroll
                for (int j = 0; j < 2; ++j)
                    acc[4 + i][2 + j] = __builtin_amdgcn_mfma_f32_16x16x32_bf16(
                        af[i][ks], b1[j][ks], acc[4 + i][2 + j], 0, 0, 0);
        __builtin_amdgcn_s_setprio(0);
        __builtin_amdgcn_sched_barrier(0);
        SBAR();
        // --- phase 3: stage B1(tau+2); counted VMC(4); Q10 = af1 x b0 -------
        if (tau + 2 < NT) STAGE(bsel, 3, tau + 2);
        if (tau < NT - 2) { VMC(4); } else { VMC(0); }
        SBAR();
        __builtin_amdgcn_sched_barrier(0);
        __builtin_amdgcn_s_setprio(1);
#pragma unroll
        for (int ks = 0; ks < 2; ++ks)
#pragma unroll
            for (int i = 0; i < 4; ++i)
#pragma unroll
                for (int j = 0; j < 2; ++j)
                    acc[4 + i][j] = __builtin_amdgcn_mfma_f32_16x16x32_bf16(
                        af[i][ks], b0[j][ks], acc[4 + i][j], 0, 0, 0);
        __builtin_amdgcn_s_setprio(0);
        __builtin_amdgcn_sched_barrier(0);
        SBAR();
    }

    // epilogue: C/D layout col(n)=lane&15, row(m)=kg*4+reg  [m89/m91 verified]
    const int baseRow = m0 + wm + (kg << 2);
    const int baseCol = n0 + wn + fr;
    float bia[4];
#pragma unroll
    for (int nf = 0; nf < 4; ++nf)
        bia[nf] = bias[baseCol + (nf >> 1) * 128 + (nf & 1) * 16];
#pragma unroll
    for (int mf = 0; mf < 8; ++mf) {
#pragma unroll
        for (int r = 0; r < 4; ++r) {
            int m = baseRow + (mf >> 2) * 128 + (mf & 3) * 16 + r;
            size_t rowoff = (size_t)m * Ndim + baseCol;
#pragma unroll
            for (int nf = 0; nf < 4; ++nf) {
                size_t off = rowoff + (nf >> 1) * 128 + (nf & 1) * 16;
                float v = acc[mf][nf][r] + bia[nf];
                if (EPI == 1) v = sigmoidf_(v);
                if (EPI == 2) v += add[off];
                if constexpr (sizeof(OutT) == 4)
                    ((float*)out)[off] = v;
                else
                    ((bf16*)out)[off] = f2bf(v);
            }
        }
    }
}

// gate GEMM + proj GEMM merged into one dispatch. 1024 blocks, XCD-swizzled.
__global__ __launch_bounds__(512, 2) void gemm_gateproj(const bf16* __restrict__ xc,
                                                        const bf16* __restrict__ gp_wT,
                                                        const float* __restrict__ gp_b,
                                                        bf16* __restrict__ gate,
                                                        const bf16* __restrict__ xn,
                                                        const bf16* __restrict__ pp_wT,
                                                        const float* __restrict__ pp_b,
                                                        bf16* __restrict__ p) {
    __shared__ __align__(16) bf16 lds[2 * 4 * 8192];   // 128 KiB
    int fid = blockIdx.x;                               // 1024 = 8 XCD * 128
    int f = (fid & 7) * 128 + (fid >> 3);               // bijective (1024%8==0)
    int by = f >> 5;                                    // m-tile 0..31
    int bx = f & 31;                                    // n-slot 0..31
    int m0 = by << 8;
    if (bx < GT_NB)
        gemm_tile256<1, bf16>(xc, gp_wT, gp_b, nullptr, gate, DD,
                              m0, bx << 8, lds);
    else
        gemm_tile256<0, bf16>(xn, pp_wT, pp_b, nullptr, p, N3,
                              m0, (bx - GT_NB) << 8, lds);
}

// final out GEMM: y = mixed @ op_w + op_b + x.  256 blocks = exactly 1/CU.
__global__ __launch_bounds__(512, 2) void gemm_out(const bf16* __restrict__ mixed,
                                                   const bf16* __restrict__ op_wT,
                                                   const float* __restrict__ op_b,
                                                   const float* __restrict__ x,
                                                   float* __restrict__ y) {
    __shared__ __align__(16) bf16 lds[2 * 4 * 8192];   // 128 KiB
    int fid = blockIdx.x;
    int f = (fid & 7) * 32 + (fid >> 3);                // bijective (256%8==0)
    int m0 = (f >> 3) << 8;
    int n0 = (f & 7) << 8;
    gemm_tile256<2, float>(mixed, op_wT, op_b, x, y, DD, m0, n0, lds);
}

// ------------------------------------------------------------- SSM scan -----
// p[b,l,h,j,s] (bf16); j=0 delta(pre-sigmoid), j=1 B, j=2 C.
// h = sigmoid(delta)*h + B;  ssm = C*h.

// phase 1: per-chunk affine composition (4 h's per 256-thread block)
__global__ __launch_bounds__(256) void scan_phase1(const bf16* __restrict__ p,
                                                   float* __restrict__ cA,
                                                   float* __restrict__ cB) {
    int c = blockIdx.x, b = blockIdx.z, s = threadIdx.x & 63;
    int h = blockIdx.y * 4 + (threadIdx.x >> 6);
    size_t base = ((size_t)(b * LL + c * CLN)) * N3 + h * (3 * DSS) + s;
    float a = 1.0f, bb = 0.0f;
#pragma unroll 8
    for (int i = 0; i < CLN; ++i) {
        float d = sigmoidf_(bf2f(p[base]));
        float Bv = bf2f(p[base + DSS]);
        a *= d;
        bb = d * bb + Bv;
        base += N3;
    }
    int idx = ((b * HH + h) * NCH + c) * DSS + s;
    cA[idx] = a;
    cB[idx] = bb;
}

// phase 3: per-block chunk-prefix from cA/cB, then replay fused with
// mixed = gate*C*h + (1-gate)*xn; block c==NCH-1 also emits h_last.
__global__ __launch_bounds__(256) void scan_phase3(const bf16* __restrict__ p,
                                                   const float* __restrict__ cA,
                                                   const float* __restrict__ cB,
                                                   const float* __restrict__ state,
                                                   const bf16* __restrict__ gate,
                                                   const bf16* __restrict__ xn,
                                                   bf16* __restrict__ mixed,
                                                   float* __restrict__ hlast) {
    int c = blockIdx.x, b = blockIdx.z, s = threadIdx.x & 63;
    int h = blockIdx.y * 4 + (threadIdx.x >> 6);
    // chunk prefix: compose chunks 0..c-1 onto the initial state
    float hp = state[(b * HH + h) * DSS + s];
    int cbase = ((b * HH + h) * NCH) * DSS + s;
    for (int cc = 0; cc < c; ++cc)
        hp = cA[cbase + cc * DSS] * hp + cB[cbase + cc * DSS];
    // replay + mix
    size_t prow = ((size_t)(b * LL + c * CLN)) * N3 + h * (3 * DSS) + s;
    size_t grow = ((size_t)(b * LL + c * CLN)) * DD + h * DSS + s;
#pragma unroll 4
    for (int i = 0; i < CLN; ++i) {
        float d = sigmoidf_(bf2f(p[prow]));
        float Bv = bf2f(p[prow + DSS]);
        float Cv = bf2f(p[prow + 2 * DSS]);
        hp = d * hp + Bv;
        float ssm = Cv * hp;
        float g = bf2f(gate[grow]);
        float xv = bf2f(xn[grow]);
        mixed[grow] = f2bf(g * ssm + (1.0f - g) * xv);
        prow += N3;
        grow += DD;
    }
    if (c == NCH - 1) hlast[(b * HH + h) * DSS + s] = hp;
}

// ---------------------------------------------------------------------------
extern "C" void kernel_launch(void* const* d_in, const int* in_sizes, int n_in,
                              void* d_out, int out_size, void* d_ws, size_t ws_size,
                              hipStream_t stream) {
    const float* x      = (const float*)d_in[0];
    const float* state  = (const float*)d_in[1];
    const float* norm_w = (const float*)d_in[2];
    const float* conv_w = (const float*)d_in[3];
    const float* conv_b = (const float*)d_in[4];
    const float* pp_w   = (const float*)d_in[5];
    const float* pp_b   = (const float*)d_in[6];
    const float* gp_w   = (const float*)d_in[7];
    const float* gp_b   = (const float*)d_in[8];
    const float* op_w   = (const float*)d_in[9];
    const float* op_b   = (const float*)d_in[10];

    float* y     = (float*)d_out;                 // M*D floats (64 MB)
    float* hlast = y + (size_t)MM * DD;           // B*H*DS floats

    // ws: xn 32MB | xcbuf 32MB (xc -> mixed) | p 96MB | cA,cB 2MB |
    //     gp_wT 8MB | op_wT 8MB                               total ~178MB
    // d_out y region (64MB): gate bf16 [0,32MB) | pp_wT bf16 [32,56MB)
    //   — both dead before gemm_out overwrites y with fp32 output.
    const size_t BHND = (size_t)BB * HH * NCH * DSS;
    char* ws = (char*)d_ws;
    bf16* xn    = (bf16*)ws;
    bf16* xcbuf = xn + (size_t)MM * DD;
    bf16* p     = xcbuf + (size_t)MM * DD;
    float* cA   = (float*)(p + (size_t)MM * N3);
    float* cB   = cA + BHND;
    bf16* gp_wT = (bf16*)(cB + BHND);
    bf16* op_wT = gp_wT + (size_t)DD * DD;
    bf16* gate  = (bf16*)y;                       // 32MB
    bf16* pp_wT = gate + (size_t)MM * DD;         // 24MB, in upper half of y
    bf16* mixed = xcbuf;

    // 1. RMSNorm + all three weight transposes (one dispatch)
    rms_transpose<<<MM + TR_NBX * TR_NBY, 256, 0, stream>>>(
        x, norm_w, xn, gp_w, op_w, pp_w, gp_wT, op_wT, pp_wT);
    // 2. causal conv + SiLU (sliding window)
    conv_silu_kernel<<<dim3(LL / CONV_LC, DD / 1024, BB), 256, 0, stream>>>(
        xn, conv_w, conv_b, xcbuf);
    // 3. gate = sigmoid(xc @ gp_w + gp_b)  AND  p = xn @ pp_w + pp_b (merged)
    gemm_gateproj<<<(GT_NB + PJ_NB) * (MM / 256), 512, 0, stream>>>(
        xcbuf, gp_wT, gp_b, gate, xn, pp_wT, pp_b, p);
    // 4. per-chunk scan summaries
    scan_phase1<<<dim3(NCH, HH / 4, BB), 256, 0, stream>>>(p, cA, cB);
    // 5. prefix + replay + mix + h_last (phase2 folded in)
    scan_phase3<<<dim3(NCH, HH / 4, BB), 256, 0, stream>>>(
        p, cA, cB, state, gate, xn, mixed, hlast);
    // 6. y = mixed @ op_w + op_b + x
    gemm_out<<<MM / 256 * (DD / 256), 512, 0, stream>>>(mixed, op_wT, op_b, x, y);
}

// Round 5
// 569.712 us; speedup vs baseline: 1.0329x; 1.0178x over previous
//
#include <hip/hip_runtime.h>
#include <math.h>

// Problem constants (MambaBlock): B=2, L=4096, D=2048, H=32, DS=64, K=4
#define BB   2
#define LL   4096
#define DD   2048
#define HH   32
#define DSS  64
#define MM   (BB * LL)        // 8192 rows
#define N3   (3 * HH * DSS)   // 6144
#define NCH  64               // scan chunks
#define CLN  64               // steps per chunk (NCH*CLN == LL)
#define EPSF 1e-6f
#define TR_NBX 320            // transpose blocks in n (64 gp + 64 op + 192 pp)
#define TR_NBY (DD / 32)      // 64 transpose blocks in k
#define NT   (DD / 64)        // 32 K-tiles of 64
#define GT_NB (DD / 256)      // 8 gate n-tiles (256-wide)
#define PJ_NB (N3 / 256)      // 24 proj n-tiles

typedef unsigned short bf16;  // raw bf16 bits — we own the representation
typedef __attribute__((ext_vector_type(8))) short bf16x8;  // MFMA A/B frag (4 VGPRs)
typedef __attribute__((ext_vector_type(4))) float f32x4;   // MFMA C/D frag

__device__ __forceinline__ float bf2f(bf16 u) {
    union { unsigned int i; float f; } v;
    v.i = ((unsigned int)u) << 16;
    return v.f;
}
__device__ __forceinline__ bf16 f2bf(float f) {
    union { float f; unsigned int u; } v;
    v.f = f;
    unsigned int r = (v.u >> 16) & 1u;       // round to nearest even
    return (bf16)((v.u + 0x7fffu + r) >> 16);
}
__device__ __forceinline__ float sigmoidf_(float v) {
    return 1.0f / (1.0f + __expf(-v));
}
__device__ __forceinline__ void gload16(const void* g, void* l) {
    __builtin_amdgcn_global_load_lds(
        (const __attribute__((address_space(1))) void*)g,
        (__attribute__((address_space(3))) void*)l, 16, 0, 0);
}

#define SBAR()  asm volatile("s_barrier" ::: "memory")
#define VMC(n)  asm volatile("s_waitcnt vmcnt(" #n ")" ::: "memory")

// -------------------- RMSNorm + all 3 weight transposes in ONE dispatch -----
// blocks [0, MM): rms row; blocks [MM, MM + TR_NBX*TR_NBY): transpose tiles.
__global__ __launch_bounds__(256) void rms_transpose(const float* __restrict__ x,
                                                     const float* __restrict__ w,
                                                     bf16* __restrict__ xn,
                                                     const float* __restrict__ gp_w,
                                                     const float* __restrict__ op_w,
                                                     const float* __restrict__ pp_w,
                                                     bf16* __restrict__ gp_wT,
                                                     bf16* __restrict__ op_wT,
                                                     bf16* __restrict__ pp_wT) {
    __shared__ float sh[32 * 33];
    int t = threadIdx.x;
    if (blockIdx.x < MM) {
        // ---- RMSNorm row ----
        int row = blockIdx.x;
        const float4* x4 = (const float4*)(x + (size_t)row * DD);
        ushort4* o4 = (ushort4*)(xn + (size_t)row * DD);
        const float4* w4 = (const float4*)w;
        float4 v0 = x4[t], v1 = x4[t + 256];
        float ss = v0.x * v0.x + v0.y * v0.y + v0.z * v0.z + v0.w * v0.w +
                   v1.x * v1.x + v1.y * v1.y + v1.z * v1.z + v1.w * v1.w;
#pragma unroll
        for (int off = 32; off >= 1; off >>= 1) ss += __shfl_down(ss, off, 64);
        if ((t & 63) == 0) sh[t >> 6] = ss;
        __syncthreads();
        float tot = sh[0] + sh[1] + sh[2] + sh[3];
        float inv = 1.0f / sqrtf(tot * (1.0f / DD) + EPSF);
        float4 wa = w4[t], wb = w4[t + 256];
        ushort4 r0, r1;
        r0.x = f2bf(v0.x * inv * wa.x); r0.y = f2bf(v0.y * inv * wa.y);
        r0.z = f2bf(v0.z * inv * wa.z); r0.w = f2bf(v0.w * inv * wa.w);
        r1.x = f2bf(v1.x * inv * wb.x); r1.y = f2bf(v1.y * inv * wb.y);
        r1.z = f2bf(v1.z * inv * wb.z); r1.w = f2bf(v1.w * inv * wb.w);
        o4[t] = r0; o4[t + 256] = r1;
    } else {
        // ---- weight transpose tile (32k x 32n), fp32 -> bf16 ----
        int id = blockIdx.x - MM;
        int bx = id % TR_NBX;
        int k0 = (id / TR_NBX) << 5;
        const float* W; bf16* WT; int Ndim;
        if (bx < 64)       { W = gp_w; WT = gp_wT; Ndim = DD; }
        else if (bx < 128) { W = op_w; WT = op_wT; Ndim = DD; bx -= 64; }
        else               { W = pp_w; WT = pp_wT; Ndim = N3; bx -= 128; }
        int n0 = bx << 5;
        float (*tl)[33] = (float (*)[33])sh;
        int tx = t & 31, ty = t >> 5;           // load: 8 k-rows x 32 n
#pragma unroll
        for (int i = 0; i < 32; i += 8)
            tl[ty + i][tx] = W[(size_t)(k0 + ty + i) * Ndim + n0 + tx];
        __syncthreads();
        int tx2 = t & 15, ty2 = t >> 4;         // store: ushort2 along k
#pragma unroll
        for (int i = 0; i < 32; i += 16) {
            int n = ty2 + i;
            ushort2 v = { f2bf(tl[tx2 * 2][n]), f2bf(tl[tx2 * 2 + 1][n]) };
            *(ushort2*)&WT[(size_t)(n0 + n) * DD + k0 + tx2 * 2] = v;
        }
    }
}

// ----------------------------------------------------- causal conv + SiLU ---
// Sliding-window: thread owns 4 d's (ushort4), walks CONV_LC l's.
#define CONV_LC 16
__global__ __launch_bounds__(256) void conv_silu_kernel(const bf16* __restrict__ xn,
                                                        const float* __restrict__ cw,
                                                        const float* __restrict__ cb,
                                                        bf16* __restrict__ xc) {
    int b = blockIdx.z;
    int l0 = blockIdx.x * CONV_LC;
    int d0 = blockIdx.y * 1024 + threadIdx.x * 4;
    float4 w[4];
    float bias[4];
#pragma unroll
    for (int j = 0; j < 4; ++j) {
        w[j] = ((const float4*)cw)[d0 + j];
        bias[j] = cb[d0 + j];
    }
    float win[3][4];
#pragma unroll
    for (int k = 0; k < 3; ++k) {
        int l = l0 - 3 + k;
        if (l >= 0) {
            ushort4 v = *(const ushort4*)&xn[((size_t)b * LL + l) * DD + d0];
            win[k][0] = bf2f(v.x); win[k][1] = bf2f(v.y);
            win[k][2] = bf2f(v.z); win[k][3] = bf2f(v.w);
        } else {
            win[k][0] = win[k][1] = win[k][2] = win[k][3] = 0.0f;
        }
    }
    size_t off = ((size_t)b * LL + l0) * DD + d0;
#pragma unroll 4
    for (int i = 0; i < CONV_LC; ++i) {
        ushort4 v = *(const ushort4*)&xn[off];
        float cur[4] = {bf2f(v.x), bf2f(v.y), bf2f(v.z), bf2f(v.w)};
        ushort4 o;
#pragma unroll
        for (int j = 0; j < 4; ++j) {
            float acc = bias[j] + win[0][j] * w[j].x + win[1][j] * w[j].y +
                        win[2][j] * w[j].z + cur[j] * w[j].w;
            float s = acc * sigmoidf_(acc);
            ((unsigned short*)&o)[j] = f2bf(s);
        }
        *(ushort4*)&xc[off] = o;
#pragma unroll
        for (int j = 0; j < 4; ++j) {
            win[0][j] = win[1][j]; win[1][j] = win[2][j]; win[2][j] = cur[j];
        }
        off += DD;
    }
}

// --------------- 256x256 3-phase MFMA GEMM (T2+T3+T4+T5) --------------------
// 8 waves (2M x 4N), per-wave 128x64 output split over both halves.
// LDS [2 buf][4 halves: A0,A1,B0,B1][128x64 chunk-swizzled] = 128 KiB.
// Per K-tile: 3 phases (R4's ph3 had NO ds_reads — its barrier pair fenced
// only a 2-load stage; Q11+Q10 share af1/b0/b1 already in regs -> merge):
//   ph0:  read af0+b0+b1 (16); stage A1,B0(tau+1); Q00 (16 MFMA)
//   ph1:  stage A0(tau+2); Q01 (16 MFMA); tail: read af1 (8)
//   ph2': stage B1(tau+2); VMC(4); Q11+Q10 (32 MFMA)
// 6 barriers/tile (was 8). FIFO vmcnt ledger: in-flight at tile start = 4
// (A0,B1 of tau+1); +4 ph0, +2 ph1, +2 ph2' = 12; VMC(4) lands the oldest 8
// = ALL of tile tau+1, leaves A0,B1(tau+2) flying (counted, never 0 = T4).
// WAR: every stage targets a region whose last read is >=1 closing barrier
// earlier (A1/B0(tau+1): last read tau-1; A0/B1(tau+2): last read tau ph0).
template <int EPI, typename OutT>
__device__ __forceinline__ void gemm_tile256(const bf16* __restrict__ A,
                                             const bf16* __restrict__ Bt,
                                             const float* __restrict__ bias,
                                             const float* __restrict__ add,
                                             OutT* __restrict__ out,
                                             int Ndim, int m0, int n0,
                                             bf16* lds) {
    const int tid  = threadIdx.x;
    const int wave = tid >> 6;
    const int lane = tid & 63;
    const int sr   = lane >> 3;                 // staging row-in-chunk 0..7
    const int gcol = ((lane & 7) ^ sr) << 3;    // pre-swizzled global col
    const bf16* gA = A  + (size_t)(m0 + wave * 16 + sr) * DD + gcol;
    const bf16* gB = Bt + (size_t)(n0 + wave * 16 + sr) * DD + gcol;
    const int ldst = wave * 1024 + lane * 8;    // linear LDS dest (elems)

    const int fr = lane & 15;
    const int kg = lane >> 4;
    const int f7 = fr & 7;
    const int wm = (wave >> 2) << 6;            // warp_m * 64
    const int wn = (wave & 3) << 5;             // warp_n * 32

    // stage one 128x64 half-tile: 2 x gload_lds(16B) per thread
    // halves: 0=A0, 1=A1, 2=B0, 3=B1
    auto STAGE = [&](int bufsel, int half, int tau) {
        const bf16* src = (half < 2 ? gA : gB) +
                          (size_t)((half & 1) << 7) * DD + tau * 64;
        bf16* dst = lds + bufsel * 32768 + half * 8192 + ldst;
        gload16(src, dst);
        gload16(src + 8 * DD, dst + 512);
    };

    f32x4 acc[8][4] = {};
    bf16x8 af[4][2], b0[2][2], b1[2][2];

    // prologue: stage tile0 fully + tile1 {A0,B1}; wait tile0 (4 newest fly).
    STAGE(0, 0, 0); STAGE(0, 3, 0); STAGE(0, 1, 0); STAGE(0, 2, 0);
    STAGE(1, 0, 1); STAGE(1, 3, 1);
    VMC(4);
    SBAR();

#pragma unroll 2
    for (int tau = 0; tau < NT; ++tau) {
        const int bsel = tau & 1;
        bf16* Ls = lds + bsel * 32768;
        // --- phase 0: read af0+b0+b1 (16); stage A1,B0(tau+1); Q00 ----------
#pragma unroll
        for (int i = 0; i < 4; ++i)
#pragma unroll
            for (int ks = 0; ks < 2; ++ks)
                af[i][ks] = *(const bf16x8*)&Ls[(wm + i * 16 + fr) * 64 +
                                               ((((ks << 2) | kg) ^ f7) << 3)];
#pragma unroll
        for (int j = 0; j < 2; ++j)
#pragma unroll
            for (int ks = 0; ks < 2; ++ks)
                b0[j][ks] = *(const bf16x8*)&Ls[2 * 8192 + (wn + j * 16 + fr) * 64 +
                                               ((((ks << 2) | kg) ^ f7) << 3)];
#pragma unroll
        for (int j = 0; j < 2; ++j)
#pragma unroll
            for (int ks = 0; ks < 2; ++ks)
                b1[j][ks] = *(const bf16x8*)&Ls[3 * 8192 + (wn + j * 16 + fr) * 64 +
                                               ((((ks << 2) | kg) ^ f7) << 3)];
        if (tau + 1 < NT) { STAGE(bsel ^ 1, 1, tau + 1); STAGE(bsel ^ 1, 2, tau + 1); }
        SBAR();
        __builtin_amdgcn_sched_barrier(0);
        __builtin_amdgcn_s_setprio(1);
#pragma unroll
        for (int ks = 0; ks < 2; ++ks)
#pragma unroll
            for (int i = 0; i < 4; ++i)
#pragma unroll
                for (int j = 0; j < 2; ++j)
                    acc[i][j] = __builtin_amdgcn_mfma_f32_16x16x32_bf16(
                        af[i][ks], b0[j][ks], acc[i][j], 0, 0, 0);
        __builtin_amdgcn_s_setprio(0);
        __builtin_amdgcn_sched_barrier(0);
        SBAR();
        // --- phase 1: stage A0(tau+2); Q01 = af0 x b1; TAIL: read af1 (8) ---
        if (tau + 2 < NT) STAGE(bsel, 0, tau + 2);
        SBAR();
        __builtin_amdgcn_sched_barrier(0);
        __builtin_amdgcn_s_setprio(1);
#pragma unroll
        for (int ks = 0; ks < 2; ++ks)
#pragma unroll
            for (int i = 0; i < 4; ++i)
#pragma unroll
                for (int j = 0; j < 2; ++j)
                    acc[i][2 + j] = __builtin_amdgcn_mfma_f32_16x16x32_bf16(
                        af[i][ks], b1[j][ks], acc[i][2 + j], 0, 0, 0);
        __builtin_amdgcn_s_setprio(0);
        __builtin_amdgcn_sched_barrier(0);
#pragma unroll
        for (int i = 0; i < 4; ++i)
#pragma unroll
            for (int ks = 0; ks < 2; ++ks)
                af[i][ks] = *(const bf16x8*)&Ls[8192 + (wm + i * 16 + fr) * 64 +
                                               ((((ks << 2) | kg) ^ f7) << 3)];
        SBAR();
        // --- phase 2': stage B1(tau+2); VMC(4); Q11+Q10 merged (32 MFMA) ----
        if (tau + 2 < NT) STAGE(bsel, 3, tau + 2);
        if (tau < NT - 2) { VMC(4); } else { VMC(0); }
        SBAR();
        __builtin_amdgcn_sched_barrier(0);
        __builtin_amdgcn_s_setprio(1);
#pragma unroll
        for (int ks = 0; ks < 2; ++ks)
#pragma unroll
            for (int i = 0; i < 4; ++i)
#pragma unroll
                for (int j = 0; j < 2; ++j)
                    acc[4 + i][2 + j] = __builtin_amdgcn_mfma_f32_16x16x32_bf16(
                        af[i][ks], b1[j][ks], acc[4 + i][2 + j], 0, 0, 0);
#pragma unroll
        for (int ks = 0; ks < 2; ++ks)
#pragma unroll
            for (int i = 0; i < 4; ++i)
#pragma unroll
                for (int j = 0; j < 2; ++j)
                    acc[4 + i][j] = __builtin_amdgcn_mfma_f32_16x16x32_bf16(
                        af[i][ks], b0[j][ks], acc[4 + i][j], 0, 0, 0);
        __builtin_amdgcn_s_setprio(0);
        __builtin_amdgcn_sched_barrier(0);
        SBAR();
    }

    // epilogue: C/D layout col(n)=lane&15, row(m)=kg*4+reg  [m89/m91 verified]
    const int baseRow = m0 + wm + (kg << 2);
    const int baseCol = n0 + wn + fr;
    float bia[4];
#pragma unroll
    for (int nf = 0; nf < 4; ++nf)
        bia[nf] = bias[baseCol + (nf >> 1) * 128 + (nf & 1) * 16];
#pragma unroll
    for (int mf = 0; mf < 8; ++mf) {
#pragma unroll
        for (int r = 0; r < 4; ++r) {
            int m = baseRow + (mf >> 2) * 128 + (mf & 3) * 16 + r;
            size_t rowoff = (size_t)m * Ndim + baseCol;
#pragma unroll
            for (int nf = 0; nf < 4; ++nf) {
                size_t off = rowoff + (nf >> 1) * 128 + (nf & 1) * 16;
                float v = acc[mf][nf][r] + bia[nf];
                if (EPI == 1) v = sigmoidf_(v);
                if (EPI == 2) v += add[off];
                if constexpr (sizeof(OutT) == 4)
                    ((float*)out)[off] = v;
                else
                    ((bf16*)out)[off] = f2bf(v);
            }
        }
    }
}

// gate GEMM + proj GEMM merged into one dispatch. 1024 blocks, XCD-swizzled.
__global__ __launch_bounds__(512, 2) void gemm_gateproj(const bf16* __restrict__ xc,
                                                        const bf16* __restrict__ gp_wT,
                                                        const float* __restrict__ gp_b,
                                                        bf16* __restrict__ gate,
                                                        const bf16* __restrict__ xn,
                                                        const bf16* __restrict__ pp_wT,
                                                        const float* __restrict__ pp_b,
                                                        bf16* __restrict__ p) {
    __shared__ __align__(16) bf16 lds[2 * 4 * 8192];   // 128 KiB
    int fid = blockIdx.x;                               // 1024 = 8 XCD * 128
    int f = (fid & 7) * 128 + (fid >> 3);               // bijective (1024%8==0)
    int by = f >> 5;                                    // m-tile 0..31
    int bx = f & 31;                                    // n-slot 0..31
    int m0 = by << 8;
    if (bx < GT_NB)
        gemm_tile256<1, bf16>(xc, gp_wT, gp_b, nullptr, gate, DD,
                              m0, bx << 8, lds);
    else
        gemm_tile256<0, bf16>(xn, pp_wT, pp_b, nullptr, p, N3,
                              m0, (bx - GT_NB) << 8, lds);
}

// final out GEMM: y = mixed @ op_w + op_b + x.  256 blocks = exactly 1/CU.
__global__ __launch_bounds__(512, 2) void gemm_out(const bf16* __restrict__ mixed,
                                                   const bf16* __restrict__ op_wT,
                                                   const float* __restrict__ op_b,
                                                   const float* __restrict__ x,
                                                   float* __restrict__ y) {
    __shared__ __align__(16) bf16 lds[2 * 4 * 8192];   // 128 KiB
    int fid = blockIdx.x;
    int f = (fid & 7) * 32 + (fid >> 3);                // bijective (256%8==0)
    int m0 = (f >> 3) << 8;
    int n0 = (f & 7) << 8;
    gemm_tile256<2, float>(mixed, op_wT, op_b, x, y, DD, m0, n0, lds);
}

// ------------------------------------------------------------- SSM scan -----
// p[b,l,h,j,s] (bf16); j=0 delta(pre-sigmoid), j=1 B, j=2 C.
// h = sigmoid(delta)*h + B;  ssm = C*h.

// phase 1: per-chunk affine composition (4 h's per 256-thread block)
__global__ __launch_bounds__(256) void scan_phase1(const bf16* __restrict__ p,
                                                   float* __restrict__ cA,
                                                   float* __restrict__ cB) {
    int c = blockIdx.x, b = blockIdx.z, s = threadIdx.x & 63;
    int h = blockIdx.y * 4 + (threadIdx.x >> 6);
    size_t base = ((size_t)(b * LL + c * CLN)) * N3 + h * (3 * DSS) + s;
    float a = 1.0f, bb = 0.0f;
#pragma unroll 8
    for (int i = 0; i < CLN; ++i) {
        float d = sigmoidf_(bf2f(p[base]));
        float Bv = bf2f(p[base + DSS]);
        a *= d;
        bb = d * bb + Bv;
        base += N3;
    }
    int idx = ((b * HH + h) * NCH + c) * DSS + s;
    cA[idx] = a;
    cB[idx] = bb;
}

// phase 3: per-block chunk-prefix from cA/cB, then replay fused with
// mixed = gate*C*h + (1-gate)*xn; block c==NCH-1 also emits h_last.
__global__ __launch_bounds__(256) void scan_phase3(const bf16* __restrict__ p,
                                                   const float* __restrict__ cA,
                                                   const float* __restrict__ cB,
                                                   const float* __restrict__ state,
                                                   const bf16* __restrict__ gate,
                                                   const bf16* __restrict__ xn,
                                                   bf16* __restrict__ mixed,
                                                   float* __restrict__ hlast) {
    int c = blockIdx.x, b = blockIdx.z, s = threadIdx.x & 63;
    int h = blockIdx.y * 4 + (threadIdx.x >> 6);
    // chunk prefix: compose chunks 0..c-1 onto the initial state
    float hp = state[(b * HH + h) * DSS + s];
    int cbase = ((b * HH + h) * NCH) * DSS + s;
    for (int cc = 0; cc < c; ++cc)
        hp = cA[cbase + cc * DSS] * hp + cB[cbase + cc * DSS];
    // replay + mix
    size_t prow = ((size_t)(b * LL + c * CLN)) * N3 + h * (3 * DSS) + s;
    size_t grow = ((size_t)(b * LL + c * CLN)) * DD + h * DSS + s;
#pragma unroll 4
    for (int i = 0; i < CLN; ++i) {
        float d = sigmoidf_(bf2f(p[prow]));
        float Bv = bf2f(p[prow + DSS]);
        float Cv = bf2f(p[prow + 2 * DSS]);
        hp = d * hp + Bv;
        float ssm = Cv * hp;
        float g = bf2f(gate[grow]);
        float xv = bf2f(xn[grow]);
        mixed[grow] = f2bf(g * ssm + (1.0f - g) * xv);
        prow += N3;
        grow += DD;
    }
    if (c == NCH - 1) hlast[(b * HH + h) * DSS + s] = hp;
}

// ---------------------------------------------------------------------------
extern "C" void kernel_launch(void* const* d_in, const int* in_sizes, int n_in,
                              void* d_out, int out_size, void* d_ws, size_t ws_size,
                              hipStream_t stream) {
    const float* x      = (const float*)d_in[0];
    const float* state  = (const float*)d_in[1];
    const float* norm_w = (const float*)d_in[2];
    const float* conv_w = (const float*)d_in[3];
    const float* conv_b = (const float*)d_in[4];
    const float* pp_w   = (const float*)d_in[5];
    const float* pp_b   = (const float*)d_in[6];
    const float* gp_w   = (const float*)d_in[7];
    const float* gp_b   = (const float*)d_in[8];
    const float* op_w   = (const float*)d_in[9];
    const float* op_b   = (const float*)d_in[10];

    float* y     = (float*)d_out;                 // M*D floats (64 MB)
    float* hlast = y + (size_t)MM * DD;           // B*H*DS floats

    // ws: xn 32MB | xcbuf 32MB (xc -> mixed) | p 96MB | cA,cB 2MB |
    //     gp_wT 8MB | op_wT 8MB                               total ~178MB
    // d_out y region (64MB): gate bf16 [0,32MB) | pp_wT bf16 [32,56MB)
    //   — both dead before gemm_out overwrites y with fp32 output.
    const size_t BHND = (size_t)BB * HH * NCH * DSS;
    char* ws = (char*)d_ws;
    bf16* xn    = (bf16*)ws;
    bf16* xcbuf = xn + (size_t)MM * DD;
    bf16* p     = xcbuf + (size_t)MM * DD;
    float* cA   = (float*)(p + (size_t)MM * N3);
    float* cB   = cA + BHND;
    bf16* gp_wT = (bf16*)(cB + BHND);
    bf16* op_wT = gp_wT + (size_t)DD * DD;
    bf16* gate  = (bf16*)y;                       // 32MB
    bf16* pp_wT = gate + (size_t)MM * DD;         // 24MB, in upper half of y
    bf16* mixed = xcbuf;

    // 1. RMSNorm + all three weight transposes (one dispatch)
    rms_transpose<<<MM + TR_NBX * TR_NBY, 256, 0, stream>>>(
        x, norm_w, xn, gp_w, op_w, pp_w, gp_wT, op_wT, pp_wT);
    // 2. causal conv + SiLU (sliding window)
    conv_silu_kernel<<<dim3(LL / CONV_LC, DD / 1024, BB), 256, 0, stream>>>(
        xn, conv_w, conv_b, xcbuf);
    // 3. gate = sigmoid(xc @ gp_w + gp_b)  AND  p = xn @ pp_w + pp_b (merged)
    gemm_gateproj<<<(GT_NB + PJ_NB) * (MM / 256), 512, 0, stream>>>(
        xcbuf, gp_wT, gp_b, gate, xn, pp_wT, pp_b, p);
    // 4. per-chunk scan summaries
    scan_phase1<<<dim3(NCH, HH / 4, BB), 256, 0, stream>>>(p, cA, cB);
    // 5. prefix + replay + mix + h_last (phase2 folded in)
    scan_phase3<<<dim3(NCH, HH / 4, BB), 256, 0, stream>>>(
        p, cA, cB, state, gate, xn, mixed, hlast);
    // 6. y = mixed @ op_w + op_b + x
    gemm_out<<<MM / 256 * (DD / 256), 512, 0, stream>>>(mixed, op_wT, op_b, x, y);
}

// Round 6
// 564.440 us; speedup vs baseline: 1.0425x; 1.0093x over previous
//
#include <hip/hip_runtime.h>
#include <math.h>

// Problem constants (MambaBlock): B=2, L=4096, D=2048, H=32, DS=64, K=4
#define BB   2
#define LL   4096
#define DD   2048
#define HH   32
#define DSS  64
#define MM   (BB * LL)        // 8192 rows
#define N3   (3 * HH * DSS)   // 6144
#define NCH  64               // scan chunks
#define CLN  64               // steps per chunk (NCH*CLN == LL)
#define EPSF 1e-6f
#define TR_NBX 320            // transpose blocks in n (64 gp + 64 op + 192 pp)
#define TR_NBY (DD / 32)      // 64 transpose blocks in k
#define NT   (DD / 64)        // 32 K-tiles of 64
#define GT_NB (DD / 256)      // 8 gate n-tiles (256-wide)
#define PJ_NB (N3 / 256)      // 24 proj n-tiles

typedef unsigned short bf16;  // raw bf16 bits — we own the representation
typedef __attribute__((ext_vector_type(8))) short bf16x8;  // MFMA A/B frag (4 VGPRs)
typedef __attribute__((ext_vector_type(4))) float f32x4;   // MFMA C/D frag

__device__ __forceinline__ float bf2f(bf16 u) {
    union { unsigned int i; float f; } v;
    v.i = ((unsigned int)u) << 16;
    return v.f;
}
__device__ __forceinline__ bf16 f2bf(float f) {
    union { float f; unsigned int u; } v;
    v.f = f;
    unsigned int r = (v.u >> 16) & 1u;       // round to nearest even
    return (bf16)((v.u + 0x7fffu + r) >> 16);
}
__device__ __forceinline__ float sigmoidf_(float v) {
    return 1.0f / (1.0f + __expf(-v));
}
__device__ __forceinline__ void gload16(const void* g, void* l) {
    __builtin_amdgcn_global_load_lds(
        (const __attribute__((address_space(1))) void*)g,
        (__attribute__((address_space(3))) void*)l, 16, 0, 0);
}

#define SBAR()  asm volatile("s_barrier" ::: "memory")
#define VMC(n)  asm volatile("s_waitcnt vmcnt(" #n ")" ::: "memory")

// -------------------- RMSNorm + all 3 weight transposes in ONE dispatch -----
// blocks [0, MM): rms row; blocks [MM, MM + TR_NBX*TR_NBY): transpose tiles.
__global__ __launch_bounds__(256) void rms_transpose(const float* __restrict__ x,
                                                     const float* __restrict__ w,
                                                     bf16* __restrict__ xn,
                                                     const float* __restrict__ gp_w,
                                                     const float* __restrict__ op_w,
                                                     const float* __restrict__ pp_w,
                                                     bf16* __restrict__ gp_wT,
                                                     bf16* __restrict__ op_wT,
                                                     bf16* __restrict__ pp_wT) {
    __shared__ float sh[32 * 33];
    int t = threadIdx.x;
    if (blockIdx.x < MM) {
        // ---- RMSNorm row ----
        int row = blockIdx.x;
        const float4* x4 = (const float4*)(x + (size_t)row * DD);
        ushort4* o4 = (ushort4*)(xn + (size_t)row * DD);
        const float4* w4 = (const float4*)w;
        float4 v0 = x4[t], v1 = x4[t + 256];
        float ss = v0.x * v0.x + v0.y * v0.y + v0.z * v0.z + v0.w * v0.w +
                   v1.x * v1.x + v1.y * v1.y + v1.z * v1.z + v1.w * v1.w;
#pragma unroll
        for (int off = 32; off >= 1; off >>= 1) ss += __shfl_down(ss, off, 64);
        if ((t & 63) == 0) sh[t >> 6] = ss;
        __syncthreads();
        float tot = sh[0] + sh[1] + sh[2] + sh[3];
        float inv = 1.0f / sqrtf(tot * (1.0f / DD) + EPSF);
        float4 wa = w4[t], wb = w4[t + 256];
        ushort4 r0, r1;
        r0.x = f2bf(v0.x * inv * wa.x); r0.y = f2bf(v0.y * inv * wa.y);
        r0.z = f2bf(v0.z * inv * wa.z); r0.w = f2bf(v0.w * inv * wa.w);
        r1.x = f2bf(v1.x * inv * wb.x); r1.y = f2bf(v1.y * inv * wb.y);
        r1.z = f2bf(v1.z * inv * wb.z); r1.w = f2bf(v1.w * inv * wb.w);
        o4[t] = r0; o4[t + 256] = r1;
    } else {
        // ---- weight transpose tile (32k x 32n), fp32 -> bf16 ----
        int id = blockIdx.x - MM;
        int bx = id % TR_NBX;
        int k0 = (id / TR_NBX) << 5;
        const float* W; bf16* WT; int Ndim;
        if (bx < 64)       { W = gp_w; WT = gp_wT; Ndim = DD; }
        else if (bx < 128) { W = op_w; WT = op_wT; Ndim = DD; bx -= 64; }
        else               { W = pp_w; WT = pp_wT; Ndim = N3; bx -= 128; }
        int n0 = bx << 5;
        float (*tl)[33] = (float (*)[33])sh;
        int tx = t & 31, ty = t >> 5;           // load: 8 k-rows x 32 n
#pragma unroll
        for (int i = 0; i < 32; i += 8)
            tl[ty + i][tx] = W[(size_t)(k0 + ty + i) * Ndim + n0 + tx];
        __syncthreads();
        int tx2 = t & 15, ty2 = t >> 4;         // store: ushort2 along k
#pragma unroll
        for (int i = 0; i < 32; i += 16) {
            int n = ty2 + i;
            ushort2 v = { f2bf(tl[tx2 * 2][n]), f2bf(tl[tx2 * 2 + 1][n]) };
            *(ushort2*)&WT[(size_t)(n0 + n) * DD + k0 + tx2 * 2] = v;
        }
    }
}

// ----------------------------------------------------- causal conv + SiLU ---
// Sliding-window: thread owns 4 d's (ushort4), walks CONV_LC l's.
#define CONV_LC 16
__global__ __launch_bounds__(256) void conv_silu_kernel(const bf16* __restrict__ xn,
                                                        const float* __restrict__ cw,
                                                        const float* __restrict__ cb,
                                                        bf16* __restrict__ xc) {
    int b = blockIdx.z;
    int l0 = blockIdx.x * CONV_LC;
    int d0 = blockIdx.y * 1024 + threadIdx.x * 4;
    float4 w[4];
    float bias[4];
#pragma unroll
    for (int j = 0; j < 4; ++j) {
        w[j] = ((const float4*)cw)[d0 + j];
        bias[j] = cb[d0 + j];
    }
    float win[3][4];
#pragma unroll
    for (int k = 0; k < 3; ++k) {
        int l = l0 - 3 + k;
        if (l >= 0) {
            ushort4 v = *(const ushort4*)&xn[((size_t)b * LL + l) * DD + d0];
            win[k][0] = bf2f(v.x); win[k][1] = bf2f(v.y);
            win[k][2] = bf2f(v.z); win[k][3] = bf2f(v.w);
        } else {
            win[k][0] = win[k][1] = win[k][2] = win[k][3] = 0.0f;
        }
    }
    size_t off = ((size_t)b * LL + l0) * DD + d0;
#pragma unroll 4
    for (int i = 0; i < CONV_LC; ++i) {
        ushort4 v = *(const ushort4*)&xn[off];
        float cur[4] = {bf2f(v.x), bf2f(v.y), bf2f(v.z), bf2f(v.w)};
        ushort4 o;
#pragma unroll
        for (int j = 0; j < 4; ++j) {
            float acc = bias[j] + win[0][j] * w[j].x + win[1][j] * w[j].y +
                        win[2][j] * w[j].z + cur[j] * w[j].w;
            float s = acc * sigmoidf_(acc);
            ((unsigned short*)&o)[j] = f2bf(s);
        }
        *(ushort4*)&xc[off] = o;
#pragma unroll
        for (int j = 0; j < 4; ++j) {
            win[0][j] = win[1][j]; win[1][j] = win[2][j]; win[2][j] = cur[j];
        }
        off += DD;
    }
}

// --------------- 256x256 3-phase MFMA GEMM (T2+T3+T4+T5) --------------------
// (unchanged from R5 — best measured GEMM; serves as control this round)
template <int EPI, typename OutT>
__device__ __forceinline__ void gemm_tile256(const bf16* __restrict__ A,
                                             const bf16* __restrict__ Bt,
                                             const float* __restrict__ bias,
                                             const float* __restrict__ add,
                                             OutT* __restrict__ out,
                                             int Ndim, int m0, int n0,
                                             bf16* lds) {
    const int tid  = threadIdx.x;
    const int wave = tid >> 6;
    const int lane = tid & 63;
    const int sr   = lane >> 3;                 // staging row-in-chunk 0..7
    const int gcol = ((lane & 7) ^ sr) << 3;    // pre-swizzled global col
    const bf16* gA = A  + (size_t)(m0 + wave * 16 + sr) * DD + gcol;
    const bf16* gB = Bt + (size_t)(n0 + wave * 16 + sr) * DD + gcol;
    const int ldst = wave * 1024 + lane * 8;    // linear LDS dest (elems)

    const int fr = lane & 15;
    const int kg = lane >> 4;
    const int f7 = fr & 7;
    const int wm = (wave >> 2) << 6;            // warp_m * 64
    const int wn = (wave & 3) << 5;             // warp_n * 32

    // stage one 128x64 half-tile: 2 x gload_lds(16B) per thread
    // halves: 0=A0, 1=A1, 2=B0, 3=B1
    auto STAGE = [&](int bufsel, int half, int tau) {
        const bf16* src = (half < 2 ? gA : gB) +
                          (size_t)((half & 1) << 7) * DD + tau * 64;
        bf16* dst = lds + bufsel * 32768 + half * 8192 + ldst;
        gload16(src, dst);
        gload16(src + 8 * DD, dst + 512);
    };

    f32x4 acc[8][4] = {};
    bf16x8 af[4][2], b0[2][2], b1[2][2];

    // prologue: stage tile0 fully + tile1 {A0,B1}; wait tile0 (4 newest fly).
    STAGE(0, 0, 0); STAGE(0, 3, 0); STAGE(0, 1, 0); STAGE(0, 2, 0);
    STAGE(1, 0, 1); STAGE(1, 3, 1);
    VMC(4);
    SBAR();

#pragma unroll 2
    for (int tau = 0; tau < NT; ++tau) {
        const int bsel = tau & 1;
        bf16* Ls = lds + bsel * 32768;
        // --- phase 0: read af0+b0+b1 (16); stage A1,B0(tau+1); Q00 ----------
#pragma unroll
        for (int i = 0; i < 4; ++i)
#pragma unroll
            for (int ks = 0; ks < 2; ++ks)
                af[i][ks] = *(const bf16x8*)&Ls[(wm + i * 16 + fr) * 64 +
                                               ((((ks << 2) | kg) ^ f7) << 3)];
#pragma unroll
        for (int j = 0; j < 2; ++j)
#pragma unroll
            for (int ks = 0; ks < 2; ++ks)
                b0[j][ks] = *(const bf16x8*)&Ls[2 * 8192 + (wn + j * 16 + fr) * 64 +
                                               ((((ks << 2) | kg) ^ f7) << 3)];
#pragma unroll
        for (int j = 0; j < 2; ++j)
#pragma unroll
            for (int ks = 0; ks < 2; ++ks)
                b1[j][ks] = *(const bf16x8*)&Ls[3 * 8192 + (wn + j * 16 + fr) * 64 +
                                               ((((ks << 2) | kg) ^ f7) << 3)];
        if (tau + 1 < NT) { STAGE(bsel ^ 1, 1, tau + 1); STAGE(bsel ^ 1, 2, tau + 1); }
        SBAR();
        __builtin_amdgcn_sched_barrier(0);
        __builtin_amdgcn_s_setprio(1);
#pragma unroll
        for (int ks = 0; ks < 2; ++ks)
#pragma unroll
            for (int i = 0; i < 4; ++i)
#pragma unroll
                for (int j = 0; j < 2; ++j)
                    acc[i][j] = __builtin_amdgcn_mfma_f32_16x16x32_bf16(
                        af[i][ks], b0[j][ks], acc[i][j], 0, 0, 0);
        __builtin_amdgcn_s_setprio(0);
        __builtin_amdgcn_sched_barrier(0);
        SBAR();
        // --- phase 1: stage A0(tau+2); Q01 = af0 x b1; TAIL: read af1 (8) ---
        if (tau + 2 < NT) STAGE(bsel, 0, tau + 2);
        SBAR();
        __builtin_amdgcn_sched_barrier(0);
        __builtin_amdgcn_s_setprio(1);
#pragma unroll
        for (int ks = 0; ks < 2; ++ks)
#pragma unroll
            for (int i = 0; i < 4; ++i)
#pragma unroll
                for (int j = 0; j < 2; ++j)
                    acc[i][2 + j] = __builtin_amdgcn_mfma_f32_16x16x32_bf16(
                        af[i][ks], b1[j][ks], acc[i][2 + j], 0, 0, 0);
        __builtin_amdgcn_s_setprio(0);
        __builtin_amdgcn_sched_barrier(0);
#pragma unroll
        for (int i = 0; i < 4; ++i)
#pragma unroll
            for (int ks = 0; ks < 2; ++ks)
                af[i][ks] = *(const bf16x8*)&Ls[8192 + (wm + i * 16 + fr) * 64 +
                                               ((((ks << 2) | kg) ^ f7) << 3)];
        SBAR();
        // --- phase 2': stage B1(tau+2); VMC(4); Q11+Q10 merged (32 MFMA) ----
        if (tau + 2 < NT) STAGE(bsel, 3, tau + 2);
        if (tau < NT - 2) { VMC(4); } else { VMC(0); }
        SBAR();
        __builtin_amdgcn_sched_barrier(0);
        __builtin_amdgcn_s_setprio(1);
#pragma unroll
        for (int ks = 0; ks < 2; ++ks)
#pragma unroll
            for (int i = 0; i < 4; ++i)
#pragma unroll
                for (int j = 0; j < 2; ++j)
                    acc[4 + i][2 + j] = __builtin_amdgcn_mfma_f32_16x16x32_bf16(
                        af[i][ks], b1[j][ks], acc[4 + i][2 + j], 0, 0, 0);
#pragma unroll
        for (int ks = 0; ks < 2; ++ks)
#pragma unroll
            for (int i = 0; i < 4; ++i)
#pragma unroll
                for (int j = 0; j < 2; ++j)
                    acc[4 + i][j] = __builtin_amdgcn_mfma_f32_16x16x32_bf16(
                        af[i][ks], b0[j][ks], acc[4 + i][j], 0, 0, 0);
        __builtin_amdgcn_s_setprio(0);
        __builtin_amdgcn_sched_barrier(0);
        SBAR();
    }

    // epilogue: C/D layout col(n)=lane&15, row(m)=kg*4+reg  [m89/m91 verified]
    const int baseRow = m0 + wm + (kg << 2);
    const int baseCol = n0 + wn + fr;
    float bia[4];
#pragma unroll
    for (int nf = 0; nf < 4; ++nf)
        bia[nf] = bias[baseCol + (nf >> 1) * 128 + (nf & 1) * 16];
#pragma unroll
    for (int mf = 0; mf < 8; ++mf) {
#pragma unroll
        for (int r = 0; r < 4; ++r) {
            int m = baseRow + (mf >> 2) * 128 + (mf & 3) * 16 + r;
            size_t rowoff = (size_t)m * Ndim + baseCol;
#pragma unroll
            for (int nf = 0; nf < 4; ++nf) {
                size_t off = rowoff + (nf >> 1) * 128 + (nf & 1) * 16;
                float v = acc[mf][nf][r] + bia[nf];
                if (EPI == 1) v = sigmoidf_(v);
                if (EPI == 2) v += add[off];
                if constexpr (sizeof(OutT) == 4)
                    ((float*)out)[off] = v;
                else
                    ((bf16*)out)[off] = f2bf(v);
            }
        }
    }
}

// gate GEMM + proj GEMM merged into one dispatch. 1024 blocks, XCD-swizzled.
__global__ __launch_bounds__(512, 2) void gemm_gateproj(const bf16* __restrict__ xc,
                                                        const bf16* __restrict__ gp_wT,
                                                        const float* __restrict__ gp_b,
                                                        bf16* __restrict__ gate,
                                                        const bf16* __restrict__ xn,
                                                        const bf16* __restrict__ pp_wT,
                                                        const float* __restrict__ pp_b,
                                                        bf16* __restrict__ p) {
    __shared__ __align__(16) bf16 lds[2 * 4 * 8192];   // 128 KiB
    int fid = blockIdx.x;                               // 1024 = 8 XCD * 128
    int f = (fid & 7) * 128 + (fid >> 3);               // bijective (1024%8==0)
    int by = f >> 5;                                    // m-tile 0..31
    int bx = f & 31;                                    // n-slot 0..31
    int m0 = by << 8;
    if (bx < GT_NB)
        gemm_tile256<1, bf16>(xc, gp_wT, gp_b, nullptr, gate, DD,
                              m0, bx << 8, lds);
    else
        gemm_tile256<0, bf16>(xn, pp_wT, pp_b, nullptr, p, N3,
                              m0, (bx - GT_NB) << 8, lds);
}

// final out GEMM: y = mixed @ op_w + op_b + x.  256 blocks = exactly 1/CU.
__global__ __launch_bounds__(512, 2) void gemm_out(const bf16* __restrict__ mixed,
                                                   const bf16* __restrict__ op_wT,
                                                   const float* __restrict__ op_b,
                                                   const float* __restrict__ x,
                                                   float* __restrict__ y) {
    __shared__ __align__(16) bf16 lds[2 * 4 * 8192];   // 128 KiB
    int fid = blockIdx.x;
    int f = (fid & 7) * 32 + (fid >> 3);                // bijective (256%8==0)
    int m0 = (f >> 3) << 8;
    int n0 = (f & 7) << 8;
    gemm_tile256<2, float>(mixed, op_wT, op_b, x, y, DD, m0, n0, lds);
}

// ------------------------------------------------------------- SSM scan -----
// p[b,l,h,j,s] (bf16); j=0 delta(pre-sigmoid), j=1 B, j=2 C.
// h = sigmoid(delta)*h + B;  ssm = C*h.
// Thread mapping (scan1/scan3): 256 thr = 8 heads x 32 lane-pairs; each lane
// owns s = {2*lp, 2*lp+1} -> all p/gate/xn accesses are ushort2 (G13).

// phase 1: per-chunk affine composition
__global__ __launch_bounds__(256) void scan_phase1(const bf16* __restrict__ p,
                                                   float* __restrict__ cA,
                                                   float* __restrict__ cB) {
    int c = blockIdx.x, b = blockIdx.z;
    int h = blockIdx.y * 8 + (threadIdx.x >> 5);
    int sp = (threadIdx.x & 31) * 2;
    size_t base = ((size_t)(b * LL + c * CLN)) * N3 + h * (3 * DSS) + sp;
    float a0 = 1.0f, b0 = 0.0f, a1 = 1.0f, b1 = 0.0f;
#pragma unroll 8
    for (int i = 0; i < CLN; ++i) {
        ushort2 dv = *(const ushort2*)&p[base];
        ushort2 Bv = *(const ushort2*)&p[base + DSS];
        float d0 = sigmoidf_(bf2f(dv.x));
        float d1 = sigmoidf_(bf2f(dv.y));
        a0 *= d0; b0 = d0 * b0 + bf2f(Bv.x);
        a1 *= d1; b1 = d1 * b1 + bf2f(Bv.y);
        base += N3;
    }
    int idx = ((b * HH + h) * NCH + c) * DSS + sp;
    *(float2*)&cA[idx] = make_float2(a0, a1);
    *(float2*)&cB[idx] = make_float2(b0, b1);
}

// phase 2: chunk-prefix precompute — hp0[b,h,c,s] = state composed with
// chunks 0..c-1.  Tiny kernel (16 blocks); removes scan3's serial prefix
// loop (up to 63 dependent scattered loads on the dispatch critical path).
__global__ __launch_bounds__(256) void scan_phase2(const float* __restrict__ cA,
                                                   const float* __restrict__ cB,
                                                   const float* __restrict__ state,
                                                   float* __restrict__ hp0) {
    int b = blockIdx.z;
    int s = threadIdx.x & 63;
    int h = blockIdx.y * 4 + (threadIdx.x >> 6);
    float hp = state[(b * HH + h) * DSS + s];
    int base = ((b * HH + h) * NCH) * DSS + s;
#pragma unroll 8
    for (int cc = 0; cc < NCH; ++cc) {
        hp0[base + cc * DSS] = hp;
        hp = cA[base + cc * DSS] * hp + cB[base + cc * DSS];
    }
}

// phase 3: load prefix, replay fused with mixed = gate*C*h + (1-gate)*xn;
// block c==NCH-1 also emits h_last.
__global__ __launch_bounds__(256) void scan_phase3(const bf16* __restrict__ p,
                                                   const float* __restrict__ hp0,
                                                   const bf16* __restrict__ gate,
                                                   const bf16* __restrict__ xn,
                                                   bf16* __restrict__ mixed,
                                                   float* __restrict__ hlast) {
    int c = blockIdx.x, b = blockIdx.z;
    int h = blockIdx.y * 8 + (threadIdx.x >> 5);
    int sp = (threadIdx.x & 31) * 2;
    float2 hp = *(const float2*)&hp0[((b * HH + h) * NCH + c) * DSS + sp];
    size_t prow = ((size_t)(b * LL + c * CLN)) * N3 + h * (3 * DSS) + sp;
    size_t grow = ((size_t)(b * LL + c * CLN)) * DD + h * DSS + sp;
#pragma unroll 4
    for (int i = 0; i < CLN; ++i) {
        ushort2 dv = *(const ushort2*)&p[prow];
        ushort2 Bv = *(const ushort2*)&p[prow + DSS];
        ushort2 Cv = *(const ushort2*)&p[prow + 2 * DSS];
        float d0 = sigmoidf_(bf2f(dv.x));
        float d1 = sigmoidf_(bf2f(dv.y));
        hp.x = d0 * hp.x + bf2f(Bv.x);
        hp.y = d1 * hp.y + bf2f(Bv.y);
        float ssm0 = bf2f(Cv.x) * hp.x;
        float ssm1 = bf2f(Cv.y) * hp.y;
        ushort2 gv = *(const ushort2*)&gate[grow];
        ushort2 xv = *(const ushort2*)&xn[grow];
        float g0 = bf2f(gv.x), g1 = bf2f(gv.y);
        ushort2 o;
        o.x = f2bf(g0 * ssm0 + (1.0f - g0) * bf2f(xv.x));
        o.y = f2bf(g1 * ssm1 + (1.0f - g1) * bf2f(xv.y));
        *(ushort2*)&mixed[grow] = o;
        prow += N3;
        grow += DD;
    }
    if (c == NCH - 1)
        *(float2*)&hlast[(b * HH + h) * DSS + sp] = hp;
}

// ---------------------------------------------------------------------------
extern "C" void kernel_launch(void* const* d_in, const int* in_sizes, int n_in,
                              void* d_out, int out_size, void* d_ws, size_t ws_size,
                              hipStream_t stream) {
    const float* x      = (const float*)d_in[0];
    const float* state  = (const float*)d_in[1];
    const float* norm_w = (const float*)d_in[2];
    const float* conv_w = (const float*)d_in[3];
    const float* conv_b = (const float*)d_in[4];
    const float* pp_w   = (const float*)d_in[5];
    const float* pp_b   = (const float*)d_in[6];
    const float* gp_w   = (const float*)d_in[7];
    const float* gp_b   = (const float*)d_in[8];
    const float* op_w   = (const float*)d_in[9];
    const float* op_b   = (const float*)d_in[10];

    float* y     = (float*)d_out;                 // M*D floats (64 MB)
    float* hlast = y + (size_t)MM * DD;           // B*H*DS floats

    // ws: xn 32MB | xcbuf 32MB (xc -> mixed) | p 96MB | cA,cB 2MB |
    //     gp_wT 8MB | op_wT 8MB                               total ~178MB
    // d_out y region (64MB): gate bf16 [0,32MB) | pp_wT bf16 [32,56MB)
    //   — both dead before gemm_out overwrites y with fp32 output.
    // hp0 (1MB) reuses the gp_wT region — dead after gemm_gateproj.
    const size_t BHND = (size_t)BB * HH * NCH * DSS;
    char* ws = (char*)d_ws;
    bf16* xn    = (bf16*)ws;
    bf16* xcbuf = xn + (size_t)MM * DD;
    bf16* p     = xcbuf + (size_t)MM * DD;
    float* cA   = (float*)(p + (size_t)MM * N3);
    float* cB   = cA + BHND;
    bf16* gp_wT = (bf16*)(cB + BHND);
    bf16* op_wT = gp_wT + (size_t)DD * DD;
    bf16* gate  = (bf16*)y;                       // 32MB
    bf16* pp_wT = gate + (size_t)MM * DD;         // 24MB, in upper half of y
    bf16* mixed = xcbuf;
    float* hp0  = (float*)gp_wT;                  // reuse: dead after step 3

    // 1. RMSNorm + all three weight transposes (one dispatch)
    rms_transpose<<<MM + TR_NBX * TR_NBY, 256, 0, stream>>>(
        x, norm_w, xn, gp_w, op_w, pp_w, gp_wT, op_wT, pp_wT);
    // 2. causal conv + SiLU (sliding window)
    conv_silu_kernel<<<dim3(LL / CONV_LC, DD / 1024, BB), 256, 0, stream>>>(
        xn, conv_w, conv_b, xcbuf);
    // 3. gate = sigmoid(xc @ gp_w + gp_b)  AND  p = xn @ pp_w + pp_b (merged)
    gemm_gateproj<<<(GT_NB + PJ_NB) * (MM / 256), 512, 0, stream>>>(
        xcbuf, gp_wT, gp_b, gate, xn, pp_wT, pp_b, p);
    // 4. per-chunk scan summaries
    scan_phase1<<<dim3(NCH, HH / 8, BB), 256, 0, stream>>>(p, cA, cB);
    // 5. chunk-prefix precompute (tiny)
    scan_phase2<<<dim3(1, HH / 4, BB), 256, 0, stream>>>(cA, cB, state, hp0);
    // 6. replay + mix + h_last
    scan_phase3<<<dim3(NCH, HH / 8, BB), 256, 0, stream>>>(
        p, hp0, gate, xn, mixed, hlast);
    // 7. y = mixed @ op_w + op_b + x
    gemm_out<<<MM / 256 * (DD / 256), 512, 0, stream>>>(mixed, op_wT, op_b, x, y);
}